// Round 12
// baseline (356.217 us; speedup 1.0000x reference)
//
#include <hip/hip_runtime.h>
#include <math.h>

#define NE   1024
#define ED   256
#define NT   131072
#define SLOTS 32

// provable bf16-RNE score-error bound: |s~ - s| <= 2*(2^-8+2^-8+2^-16)*|z||w| + eps
#define THR_REL 0.016f
#define THR_ABS 0.02f

typedef __attribute__((ext_vector_type(8))) short short8;
typedef __attribute__((ext_vector_type(4))) float f32x4;

__device__ inline unsigned short f2bf(float f) {
    unsigned u = __float_as_uint(f);
    unsigned r = (u + 0x7FFFu + ((u >> 16) & 1u)) >> 16;   // RNE
    return (unsigned short)r;
}

__device__ inline void gl_lds16(const void* g, void* l) {
    __builtin_amdgcn_global_load_lds(
        (const __attribute__((address_space(1))) unsigned int*)g,
        (__attribute__((address_space(3))) unsigned int*)l, 16, 0, 0);
}

// packed candidate: (q(s~) << 16) | code ; q monotone in s~ so u32-min is
// lexicographic (s~, code)-min. q = floor((s + 1024) * 16), clamped.
__device__ inline unsigned pack_cand(float s, int code) {
    float qf = (s + 1024.f) * 16.f;
    int q = (int)qf;
    q = q < 0 ? 0 : (q > 65535 ? 65535 : q);
    return ((unsigned)q << 16) | (unsigned)code;
}

// ---------------------------------------------------------------------------
// ws layout:
//   0        wnorm  f32[1024]
//   4096     counts int[1024]
//   8192     wmax   f32[1]
//   8448     wb     bf16[1024*256]    (512 KB)
//   532736   cnt    u32[131072]       (512 KB)
//   1057024  cand   u32[131072*32]    (16 MB)   need = 17834240
// ---------------------------------------------------------------------------

__global__ __launch_bounds__(256) void vq_prep(const float* __restrict__ w,
                                               float* __restrict__ wnorm,
                                               int* __restrict__ counts,
                                               unsigned short* __restrict__ wb) {
    int c = blockIdx.x * 256 + threadIdx.x;
    if (c < NE) {
        const float4* row = reinterpret_cast<const float4*>(w + (size_t)c * ED);
        ushort4* wbr = reinterpret_cast<ushort4*>(wb + (size_t)c * ED);
        float s = 0.f;
#pragma unroll 8
        for (int i = 0; i < ED / 4; ++i) {
            float4 v = row[i];
            s += v.x * v.x + v.y * v.y + v.z * v.z + v.w * v.w;
            ushort4 o;
            o.x = f2bf(v.x); o.y = f2bf(v.y); o.z = f2bf(v.z); o.w = f2bf(v.w);
            wbr[i] = o;
        }
        wnorm[c] = s;
        counts[c] = 0;
    }
}

__global__ __launch_bounds__(1024) void vq_wmax(const float* __restrict__ wnorm,
                                                float* __restrict__ wmax) {
    __shared__ float red[16];
    int tid = threadIdx.x;
    float v = wnorm[tid];
#pragma unroll
    for (int m = 32; m >= 1; m >>= 1) v = fmaxf(v, __shfl_xor(v, m, 64));
    if ((tid & 63) == 0) red[tid >> 6] = v;
    __syncthreads();
    if (tid == 0) {
        float m = red[0];
#pragma unroll
        for (int i = 1; i < 16; ++i) m = fmaxf(m, red[i]);
        wmax[0] = sqrtf(m);
    }
}

// W-stationary score kernel, swapped MFMA operands: C[row=code][col=token].
// TOKEN-AMORTIZATION reshape: 512 blocks x 256 threads, 4 waves x 64 tokens
// = 256 tokens/block. Each staged wf fragment now feeds 4 MFMAs (4 mi) ->
// per-token staging/ds_read/epilogue cost HALVED vs round 11. 16 stages of
// 64 codes through 32 KB LDS (single buffer), same proven epilogue cadence.
__global__ __launch_bounds__(256) void vq_score5(const float* __restrict__ z,
                                                 const unsigned short* __restrict__ wb,
                                                 const float* __restrict__ wnorm,
                                                 const float* __restrict__ wmaxp,
                                                 unsigned* __restrict__ cnt,
                                                 unsigned* __restrict__ cand) {
    __shared__ __align__(16) unsigned short wlds[16384];   // 32 KB
    __shared__ float wn_lds[NE];                           // 4 KB

    const int tid  = threadIdx.x;
    const int lane = tid & 63;
    const int wv_  = tid >> 6;          // 0..3
    const int l15  = lane & 15;
    const int l4   = lane >> 4;
    const int row0 = blockIdx.x * 256 + wv_ * 64;

    // ---- issue stage 0 FIRST so it overlaps the z-load/A-prep below ----
    // 32 frags of 1 KB (s = nj*8+kg, nj<4); wave wv_ stages s = wv_*8+p
#pragma unroll
    for (int p = 0; p < 8; ++p) {
        int s  = wv_ * 8 + p;
        int nj = s >> 3, kg = s & 7;
        int j  = nj * 16 + l15;                          // stage 0
        gl_lds16(wb + (size_t)j * ED + kg * 32 + l4 * 8, &wlds[s * 512]);
    }

    // wnorm -> LDS (256 threads x float4)
    reinterpret_cast<float4*>(wn_lds)[tid] = reinterpret_cast<const float4*>(wnorm)[tid];

    // ---- Z fragments: B-operand layout (col=token=l15, k=kg*32+l4*8+i) ----
    short8 a[4][8];
    float thrR[4], mn[4];
    int cnt_reg[4];
    {
        float wmax = wmaxp[0];
#pragma unroll
        for (int mi = 0; mi < 4; ++mi) {
            const float* zr = z + (size_t)(row0 + mi * 16 + l15) * ED;
            float s = 0.f;
#pragma unroll
            for (int kg = 0; kg < 8; ++kg) {
                int k0 = kg * 32 + l4 * 8;
                float4 p = *reinterpret_cast<const float4*>(zr + k0);
                float4 q = *reinterpret_cast<const float4*>(zr + k0 + 4);
                s += p.x * p.x + p.y * p.y + p.z * p.z + p.w * p.w
                   + q.x * q.x + q.y * q.y + q.z * q.z + q.w * q.w;
                short8 t;
                t[0] = (short)f2bf(p.x); t[1] = (short)f2bf(p.y);
                t[2] = (short)f2bf(p.z); t[3] = (short)f2bf(p.w);
                t[4] = (short)f2bf(q.x); t[5] = (short)f2bf(q.y);
                t[6] = (short)f2bf(q.z); t[7] = (short)f2bf(q.w);
                a[mi][kg] = t;
            }
            s += __shfl_xor(s, 16, 64);
            s += __shfl_xor(s, 32, 64);
            thrR[mi] = THR_REL * sqrtf(s) * wmax + THR_ABS;
            mn[mi] = 3.4e38f;
            cnt_reg[mi] = 0;
        }
    }

    asm volatile("s_waitcnt vmcnt(0) lgkmcnt(0)" ::: "memory");
    __builtin_amdgcn_s_barrier();

    for (int st = 0; st < 16; ++st) {
        const int c0 = st * 64;

        for (int base = 0; base < 4; base += 2) {   // 2 batches of 2 tiles
            f32x4 acc[2][4];   // [tb][mi]
#pragma unroll
            for (int tb = 0; tb < 2; ++tb)
#pragma unroll
                for (int mi = 0; mi < 4; ++mi) acc[tb][mi] = {0.f, 0.f, 0.f, 0.f};

#pragma unroll
            for (int tb = 0; tb < 2; ++tb)
#pragma unroll
                for (int kg = 0; kg < 8; ++kg) {
                    short8 wf = *reinterpret_cast<const short8*>(
                        &wlds[(((base + tb) * 8 + kg) * 512) + lane * 8]);
                    // swapped: A = codes (W), B = tokens (Z); wf feeds 4 MFMAs
                    acc[tb][0] = __builtin_amdgcn_mfma_f32_16x16x32_bf16(wf, a[0][kg], acc[tb][0], 0, 0, 0);
                    acc[tb][1] = __builtin_amdgcn_mfma_f32_16x16x32_bf16(wf, a[1][kg], acc[tb][1], 0, 0, 0);
                    acc[tb][2] = __builtin_amdgcn_mfma_f32_16x16x32_bf16(wf, a[2][kg], acc[tb][2], 0, 0, 0);
                    acc[tb][3] = __builtin_amdgcn_mfma_f32_16x16x32_bf16(wf, a[3][kg], acc[tb][3], 0, 0, 0);
                }

            // wnorm per code: codes of this thread = c0+(base+tb)*16 + l4*4 + r
            float4 wnv[2];
#pragma unroll
            for (int tb = 0; tb < 2; ++tb)
                wnv[tb] = *reinterpret_cast<const float4*>(
                    &wn_lds[c0 + (base + tb) * 16 + l4 * 4]);

            // scores in place; in-thread min per token
            float tmin[4] = {3.4e38f, 3.4e38f, 3.4e38f, 3.4e38f};
#pragma unroll
            for (int tb = 0; tb < 2; ++tb) {
                float wr[4] = {wnv[tb].x, wnv[tb].y, wnv[tb].z, wnv[tb].w};
#pragma unroll
                for (int mi = 0; mi < 4; ++mi)
#pragma unroll
                    for (int r = 0; r < 4; ++r) {
                        float s = fmaf(-2.f, acc[tb][mi][r], wr[r]);
                        acc[tb][mi][r] = s;
                        tmin[mi] = fminf(tmin[mi], s);
                    }
            }
            // cross-l4 reduce (2 shuffles), fold into running min
#pragma unroll
            for (int mi = 0; mi < 4; ++mi) {
                float v = tmin[mi];
                v = fminf(v, __shfl_xor(v, 16, 64));
                v = fminf(v, __shfl_xor(v, 32, 64));
                mn[mi] = fminf(mn[mi], v);
            }

            // keep masks: bit tb*4+r
            unsigned km[4] = {0u, 0u, 0u, 0u};
#pragma unroll
            for (int tb = 0; tb < 2; ++tb)
#pragma unroll
                for (int mi = 0; mi < 4; ++mi)
#pragma unroll
                    for (int r = 0; r < 4; ++r)
                        if (acc[tb][mi][r] <= mn[mi] + thrR[mi])
                            km[mi] |= 1u << (tb * 4 + r);

            if (__any((km[0] | km[1] | km[2] | km[3]) != 0u)) {
#pragma unroll
                for (int mi = 0; mi < 4; ++mi) {
                    int kc = __popc(km[mi]);
                    int b = __shfl_xor(kc, 16, 64);   // l4 ^ 1
                    int c = __shfl_xor(kc, 32, 64);   // l4 ^ 2
                    int d = __shfl_xor(b, 32, 64);    // l4 ^ 3
                    int tot = kc + b + c + d;
                    if (tot > 0) {
                        int pfx = (l4 == 1) ? b
                                : (l4 == 2) ? (c + d)
                                : (l4 == 3) ? (b + c + d) : 0;
                        int tok = row0 + mi * 16 + l15;
                        int o = 0;
#pragma unroll
                        for (int tb = 0; tb < 2; ++tb)
#pragma unroll
                            for (int r = 0; r < 4; ++r)
                                if (km[mi] & (1u << (tb * 4 + r))) {
                                    int pos = cnt_reg[mi] + pfx + o;
                                    if (pos < SLOTS)
                                        cand[(size_t)tok * SLOTS + pos] =
                                            pack_cand(acc[tb][mi][r],
                                                      c0 + (base + tb) * 16 + l4 * 4 + r);
                                    ++o;
                                }
                        cnt_reg[mi] += tot;
                    }
                }
            }
        }

        // re-stage next 64 codes (single buffer: all waves done reading)
        if (st < 15) {
            asm volatile("s_waitcnt lgkmcnt(0)" ::: "memory");
            __builtin_amdgcn_s_barrier();
#pragma unroll
            for (int p = 0; p < 8; ++p) {
                int s  = wv_ * 8 + p;
                int nj = s >> 3, kg = s & 7;
                int j  = (st + 1) * 64 + nj * 16 + l15;
                gl_lds16(wb + (size_t)j * ED + kg * 32 + l4 * 8, &wlds[s * 512]);
            }
            asm volatile("s_waitcnt vmcnt(0) lgkmcnt(0)" ::: "memory");
            __builtin_amdgcn_s_barrier();
        }
    }

    // final per-token candidate counts (4 l4-lanes agree; l4==0 writes)
    if (l4 == 0) {
#pragma unroll
        for (int mi = 0; mi < 4; ++mi)
            cnt[row0 + mi * 16 + l15] = (unsigned)cnt_reg[mi];
    }
}

// Exact fp32 refine: wave-parallel prune on packed (q,code), then exact
// evaluation of survivors; fused gather of z_q and counts histogram.
__global__ __launch_bounds__(256) void vq_refine(const float* __restrict__ z,
                                                 const float* __restrict__ w,
                                                 const float* __restrict__ wnorm,
                                                 const float* __restrict__ wmaxp,
                                                 const unsigned* __restrict__ cnt,
                                                 const unsigned* __restrict__ cand,
                                                 int* __restrict__ counts,
                                                 float* __restrict__ out) {
    const int lane = threadIdx.x & 63;
    const int t = blockIdx.x * 4 + (threadIdx.x >> 6);
    float4 zv = reinterpret_cast<const float4*>(z + (size_t)t * ED)[lane];
    unsigned n = cnt[t];
    float bs = 3.4e38f;
    int bj = NE;

    if (n >= 1u && n <= (unsigned)SLOTS) {
        unsigned pk = 0xFFFFFFFFu;
        if (lane < (int)n) pk = cand[(size_t)t * SLOTS + lane];
        unsigned pmin = pk;
#pragma unroll
        for (int m = 1; m < 64; m <<= 1) {
            unsigned o = __shfl_xor(pmin, m, 64);
            pmin = o < pmin ? o : pmin;
        }
        // same thr formula as score; margin covers 2 quantization steps
        float zn = zv.x * zv.x + zv.y * zv.y + zv.z * zv.z + zv.w * zv.w;
#pragma unroll
        for (int m = 1; m < 64; m <<= 1) zn += __shfl_xor(zn, m, 64);
        float thr = THR_REL * sqrtf(zn) * wmaxp[0] + THR_ABS;
        unsigned margin = (unsigned)(16.f * thr) + 2u;
        unsigned qmin = pmin >> 16;
        bool keep = (lane < (int)n) && ((pk >> 16) <= qmin + margin);
        unsigned long long mask = __ballot(keep);
        while (mask) {
            int c = __ffsll(mask) - 1;
            mask &= mask - 1;
            int j = (int)(__shfl(pk, c, 64) & 0xFFFFu);
            float4 wv = reinterpret_cast<const float4*>(w + (size_t)j * ED)[lane];
            float d = fmaf(zv.x, wv.x, fmaf(zv.y, wv.y, fmaf(zv.z, wv.z, zv.w * wv.w)));
#pragma unroll
            for (int m = 1; m < 64; m <<= 1) d += __shfl_xor(d, m, 64);
            float s = fmaf(-2.f, d, wnorm[j]);
            if (s < bs || (s == bs && j < bj)) { bs = s; bj = j; }
        }
    } else {
        for (int j = 0; j < NE; ++j) {
            float4 wv = reinterpret_cast<const float4*>(w + (size_t)j * ED)[lane];
            float d = fmaf(zv.x, wv.x, fmaf(zv.y, wv.y, fmaf(zv.z, wv.z, zv.w * wv.w)));
#pragma unroll
            for (int m = 1; m < 64; m <<= 1) d += __shfl_xor(d, m, 64);
            float s = fmaf(-2.f, d, wnorm[j]);
            if (s < bs || (s == bs && j < bj)) { bs = s; bj = j; }
        }
    }
    float4 bw = reinterpret_cast<const float4*>(w + (size_t)bj * ED)[lane];
    reinterpret_cast<float4*>(out + (size_t)t * ED)[lane] = bw;
    if (lane == 0) atomicAdd(&counts[bj], 1);
}

__global__ __launch_bounds__(1024) void vq_pplx(const int* __restrict__ counts,
                                                float* __restrict__ out) {
    __shared__ float red[16];
    int tid = threadIdx.x;
    float e = (float)counts[tid] * (1.0f / (float)NT);
    float t = -e * logf(e + 1e-10f);
#pragma unroll
    for (int m = 32; m >= 1; m >>= 1) t += __shfl_down(t, m, 64);
    if ((tid & 63) == 0) red[tid >> 6] = t;
    __syncthreads();
    if (tid < 16) {
        float s = red[tid];
#pragma unroll
        for (int m = 8; m >= 1; m >>= 1) s += __shfl_down(s, m, 16);
        if (tid == 0) out[(size_t)NT * ED] = expf(s);
    }
}

// ======================= fallback (round-1, fp32 VALU) =======================
#define TM 64
#define TN 64
#define KC 64

__global__ __launch_bounds__(256) void vq_prep0(const float* __restrict__ w,
                                                float* __restrict__ wnorm,
                                                int* __restrict__ counts) {
    int c = blockIdx.x * blockDim.x + threadIdx.x;
    if (c < NE) {
        const float4* row = reinterpret_cast<const float4*>(w + (size_t)c * ED);
        float s = 0.f;
#pragma unroll 8
        for (int i = 0; i < ED / 4; ++i) {
            float4 v = row[i];
            s += v.x * v.x + v.y * v.y + v.z * v.z + v.w * v.w;
        }
        wnorm[c] = s;
        counts[c] = 0;
    }
}

__global__ __launch_bounds__(256) void vq_argmin0(const float* __restrict__ z,
                                                  const float* __restrict__ w,
                                                  const float* __restrict__ wnorm,
                                                  int* __restrict__ idx_out,
                                                  int* __restrict__ counts) {
    __shared__ float zs[ED][TM];
    __shared__ float wsh[KC][TN];
    const int tid  = threadIdx.x;
    const int row0 = blockIdx.x * TM;
    const int cg   = tid & 15;
    const int tg   = tid >> 4;
#pragma unroll
    for (int p = 0; p < 16; ++p) {
        int f = p * 256 + tid;
        int k = f >> 4;
        int g = f & 15;
        float4 v;
        v.x = z[(size_t)(row0 + g * 4 + 0) * ED + k];
        v.y = z[(size_t)(row0 + g * 4 + 1) * ED + k];
        v.z = z[(size_t)(row0 + g * 4 + 2) * ED + k];
        v.w = z[(size_t)(row0 + g * 4 + 3) * ED + k];
        *reinterpret_cast<float4*>(&zs[k][g * 4]) = v;
    }
    float best[4];
    int   bidx[4];
#pragma unroll
    for (int i = 0; i < 4; ++i) { best[i] = 3.4e38f; bidx[i] = 0; }
    for (int ct = 0; ct < NE / TN; ++ct) {
        const int c0 = ct * TN;
        float acc[4][4];
#pragma unroll
        for (int i = 0; i < 4; ++i)
#pragma unroll
            for (int j = 0; j < 4; ++j) acc[i][j] = 0.f;
        for (int kc = 0; kc < ED / KC; ++kc) {
            __syncthreads();
#pragma unroll
            for (int p = 0; p < 4; ++p) {
                int f = p * 256 + tid;
                int k = f >> 4;
                int g = f & 15;
                float4 v;
                v.x = w[(size_t)(c0 + g * 4 + 0) * ED + kc * KC + k];
                v.y = w[(size_t)(c0 + g * 4 + 1) * ED + kc * KC + k];
                v.z = w[(size_t)(c0 + g * 4 + 2) * ED + kc * KC + k];
                v.w = w[(size_t)(c0 + g * 4 + 3) * ED + kc * KC + k];
                *reinterpret_cast<float4*>(&wsh[k][g * 4]) = v;
            }
            __syncthreads();
#pragma unroll 8
            for (int k = 0; k < KC; ++k) {
                float4 zv = *reinterpret_cast<const float4*>(&zs[kc * KC + k][tg * 4]);
                float4 wv = *reinterpret_cast<const float4*>(&wsh[k][cg * 4]);
                float zr[4] = { zv.x, zv.y, zv.z, zv.w };
                float wr[4] = { wv.x, wv.y, wv.z, wv.w };
#pragma unroll
                for (int i = 0; i < 4; ++i)
#pragma unroll
                    for (int j = 0; j < 4; ++j)
                        acc[i][j] = fmaf(zr[i], wr[j], acc[i][j]);
            }
        }
#pragma unroll
        for (int j = 0; j < 4; ++j) {
            int c = c0 + cg * 4 + j;
            float wn = wnorm[c];
#pragma unroll
            for (int i = 0; i < 4; ++i) {
                float s = fmaf(-2.f, acc[i][j], wn);
                if (s < best[i]) { best[i] = s; bidx[i] = c; }
            }
        }
    }
#pragma unroll
    for (int m = 1; m < 16; m <<= 1) {
#pragma unroll
        for (int i = 0; i < 4; ++i) {
            float ov = __shfl_xor(best[i], m, 64);
            int   oi = __shfl_xor(bidx[i], m, 64);
            if (ov < best[i] || (ov == best[i] && oi < bidx[i])) {
                best[i] = ov; bidx[i] = oi;
            }
        }
    }
    if (cg == 0) {
#pragma unroll
        for (int i = 0; i < 4; ++i) {
            int t = row0 + tg * 4 + i;
            idx_out[t] = bidx[i];
            atomicAdd(&counts[bidx[i]], 1);
        }
    }
}

__global__ __launch_bounds__(256) void vq_gather0(const float* __restrict__ w,
                                                  const int* __restrict__ idx,
                                                  float* __restrict__ out) {
    int tid = threadIdx.x;
    int t   = blockIdx.x * 4 + (tid >> 6);
    int c4  = tid & 63;
    int id  = idx[t];
    float4 v = reinterpret_cast<const float4*>(w + (size_t)id * ED)[c4];
    reinterpret_cast<float4*>(out + (size_t)t * ED)[c4] = v;
}
// ============================================================================

extern "C" void kernel_launch(void* const* d_in, const int* in_sizes, int n_in,
                              void* d_out, int out_size, void* d_ws, size_t ws_size,
                              hipStream_t stream) {
    const float* z = (const float*)d_in[0];
    const float* w = (const float*)d_in[1];
    float* out = (float*)d_out;
    char* ws = (char*)d_ws;

    float*          wnorm  = (float*)ws;
    int*            counts = (int*)(ws + 4096);
    float*          wmax   = (float*)(ws + 8192);
    unsigned short* wb     = (unsigned short*)(ws + 8448);
    unsigned*       cnt    = (unsigned*)(ws + 532736);
    unsigned*       cand   = (unsigned*)(ws + 1057024);
    const size_t need = 1057024 + (size_t)NT * SLOTS * 4;

    if (ws_size >= need) {
        vq_prep<<<4, 256, 0, stream>>>(w, wnorm, counts, wb);
        vq_wmax<<<1, 1024, 0, stream>>>(wnorm, wmax);
        vq_score5<<<NT / 256, 256, 0, stream>>>(z, wb, wnorm, wmax, cnt, cand);
        vq_refine<<<NT / 4, 256, 0, stream>>>(z, w, wnorm, wmax, cnt, cand, counts, out);
        vq_pplx<<<1, 1024, 0, stream>>>(counts, out);
    } else {
        int* idxw = (int*)(ws + 8192);
        vq_prep0<<<(NE + 255) / 256, 256, 0, stream>>>(w, wnorm, counts);
        vq_argmin0<<<NT / TM, 256, 0, stream>>>(z, w, wnorm, idxw, counts);
        vq_gather0<<<NT / 4, 256, 0, stream>>>(w, idxw, out);
        vq_pplx<<<1, 1024, 0, stream>>>(counts, out);
    }
}

// Round 13
// 299.143 us; speedup vs baseline: 1.1908x; 1.1908x over previous
//
#include <hip/hip_runtime.h>
#include <math.h>

#define NE   1024
#define ED   256
#define NT   131072
#define SLOTS 32

// provable bf16-RNE score-error bound: |s~ - s| <= 2*(2^-8+2^-8+2^-16)*|z||w| + eps
#define THR_REL 0.016f
#define THR_ABS 0.02f

typedef __attribute__((ext_vector_type(8)))  short short8;
typedef __attribute__((ext_vector_type(4)))  float f32x4;
typedef __attribute__((ext_vector_type(16))) float f32x16;

__device__ inline unsigned short f2bf(float f) {
    unsigned u = __float_as_uint(f);
    unsigned r = (u + 0x7FFFu + ((u >> 16) & 1u)) >> 16;   // RNE
    return (unsigned short)r;
}

__device__ inline void gl_lds16(const void* g, void* l) {
    __builtin_amdgcn_global_load_lds(
        (const __attribute__((address_space(1))) unsigned int*)g,
        (__attribute__((address_space(3))) unsigned int*)l, 16, 0, 0);
}

// packed candidate: (q(s~) << 16) | code ; q monotone in s~ so u32-min is
// lexicographic (s~, code)-min. q = floor((s + 1024) * 16), clamped.
__device__ inline unsigned pack_cand(float s, int code) {
    float qf = (s + 1024.f) * 16.f;
    int q = (int)qf;
    q = q < 0 ? 0 : (q > 65535 ? 65535 : q);
    return ((unsigned)q << 16) | (unsigned)code;
}

// ---------------------------------------------------------------------------
// ws layout:
//   0        wnorm  f32[1024]
//   4096     counts int[1024]
//   8192     wmax   f32[1]
//   8448     wb     bf16[1024*256]    (512 KB)  — 32x32x16 A-frag layout, *(-2)
//   532736   cnt    u32[131072]       (512 KB)
//   1057024  cand   u32[131072*32]    (16 MB)   need = 17834240
// ---------------------------------------------------------------------------

// wb fragment layout for A-operand of mfma_32x32x16 (codes on rows), values
// PRESCALED by -2 (exact):  frag f = (c>>5)*16 + kg  is 1 KB; within frag,
// lane = (c&31) + 32*hi holds k = kg*16 + hi*8 + i  (i = 0..7).
__global__ __launch_bounds__(256) void vq_prep(const float* __restrict__ w,
                                               float* __restrict__ wnorm,
                                               int* __restrict__ counts,
                                               unsigned short* __restrict__ wb) {
    int c = blockIdx.x * 256 + threadIdx.x;
    if (c < NE) {
        const float* row = w + (size_t)c * ED;
        float s = 0.f;
#pragma unroll
        for (int kg = 0; kg < 16; ++kg) {
#pragma unroll
            for (int hi = 0; hi < 2; ++hi) {
                int k0 = kg * 16 + hi * 8;
                float4 p = *reinterpret_cast<const float4*>(row + k0);
                float4 q = *reinterpret_cast<const float4*>(row + k0 + 4);
                s += p.x * p.x + p.y * p.y + p.z * p.z + p.w * p.w
                   + q.x * q.x + q.y * q.y + q.z * q.z + q.w * q.w;
                short8 t;
                t[0] = (short)f2bf(-2.f * p.x); t[1] = (short)f2bf(-2.f * p.y);
                t[2] = (short)f2bf(-2.f * p.z); t[3] = (short)f2bf(-2.f * p.w);
                t[4] = (short)f2bf(-2.f * q.x); t[5] = (short)f2bf(-2.f * q.y);
                t[6] = (short)f2bf(-2.f * q.z); t[7] = (short)f2bf(-2.f * q.w);
                *reinterpret_cast<short8*>(
                    wb + (size_t)((c >> 5) * 16 + kg) * 512
                       + ((c & 31) + 32 * hi) * 8) = t;
            }
        }
        wnorm[c] = s;
        counts[c] = 0;
    }
}

__global__ __launch_bounds__(1024) void vq_wmax(const float* __restrict__ wnorm,
                                                float* __restrict__ wmax) {
    __shared__ float red[16];
    int tid = threadIdx.x;
    float v = wnorm[tid];
#pragma unroll
    for (int m = 32; m >= 1; m >>= 1) v = fmaxf(v, __shfl_xor(v, m, 64));
    if ((tid & 63) == 0) red[tid >> 6] = v;
    __syncthreads();
    if (tid == 0) {
        float m = red[0];
#pragma unroll
        for (int i = 1; i < 16; ++i) m = fmaxf(m, red[i]);
        wmax[0] = sqrtf(m);
    }
}

// 32x32x16-MFMA score kernel, swapped operands: C[row=code][col=token].
// 1024 blocks x 256 threads (4 waves x 32 tokens). 8 stages of 128 codes
// through 64 KB LDS. acc initialized from wnorm; wb prescaled by -2 so the
// accumulator IS the score after the K loop (no epilogue fma). A token's
// 32 scores/tile live on 2 partner lanes -> 1 shuffle min, 1 shuffle prefix.
__global__ __launch_bounds__(256) void vq_score6(const float* __restrict__ z,
                                                 const unsigned short* __restrict__ wb,
                                                 const float* __restrict__ wnorm,
                                                 const float* __restrict__ wmaxp,
                                                 unsigned* __restrict__ cnt,
                                                 unsigned* __restrict__ cand) {
    __shared__ __align__(16) unsigned short wlds[32768];   // 64 KB
    __shared__ float wn_lds[NE];                           // 4 KB

    const int tid  = threadIdx.x;
    const int lane = tid & 63;
    const int wv_  = tid >> 6;          // 0..3
    const int l31  = lane & 31;
    const int hi   = lane >> 5;         // 0/1: k-half and C-row +4 offset
    const int row0 = blockIdx.x * 128 + wv_ * 32;
    const int tok  = row0 + l31;

    // ---- issue stage 0 FIRST (64 frags of 1 KB; wave stages s = wv_*16+p) ----
#pragma unroll
    for (int p = 0; p < 16; ++p) {
        int s = wv_ * 16 + p;
        gl_lds16(wb + (size_t)s * 512 + lane * 8, &wlds[s * 512]);
    }

    // wnorm -> LDS
    reinterpret_cast<float4*>(wn_lds)[tid] = reinterpret_cast<const float4*>(wnorm)[tid];

    // ---- Z fragments: B-operand (col=token=l31, k = kg*16 + hi*8 + i) ----
    short8 z16[16];
    float thrR, mn;
    int cnt_reg = 0;
    {
        const float* zr = z + (size_t)tok * ED;
        float s = 0.f;
#pragma unroll
        for (int kg = 0; kg < 16; ++kg) {
            int k0 = kg * 16 + hi * 8;
            float4 p = *reinterpret_cast<const float4*>(zr + k0);
            float4 q = *reinterpret_cast<const float4*>(zr + k0 + 4);
            s += p.x * p.x + p.y * p.y + p.z * p.z + p.w * p.w
               + q.x * q.x + q.y * q.y + q.z * q.z + q.w * q.w;
            short8 t;
            t[0] = (short)f2bf(p.x); t[1] = (short)f2bf(p.y);
            t[2] = (short)f2bf(p.z); t[3] = (short)f2bf(p.w);
            t[4] = (short)f2bf(q.x); t[5] = (short)f2bf(q.y);
            t[6] = (short)f2bf(q.z); t[7] = (short)f2bf(q.w);
            z16[kg] = t;
        }
        s += __shfl_xor(s, 32, 64);   // partner holds the other k-half
        thrR = THR_REL * sqrtf(s) * wmaxp[0] + THR_ABS;
        mn = 3.4e38f;
    }

    asm volatile("s_waitcnt vmcnt(0) lgkmcnt(0)" ::: "memory");
    __builtin_amdgcn_s_barrier();

#define ACC_INIT(acc_, cb_) do {                                              \
    float4 w0_ = *reinterpret_cast<const float4*>(&wn_lds[(cb_) + 4 * hi]);   \
    float4 w1_ = *reinterpret_cast<const float4*>(&wn_lds[(cb_) + 8 + 4 * hi]); \
    float4 w2_ = *reinterpret_cast<const float4*>(&wn_lds[(cb_) + 16 + 4 * hi]); \
    float4 w3_ = *reinterpret_cast<const float4*>(&wn_lds[(cb_) + 24 + 4 * hi]); \
    acc_[0] = w0_.x; acc_[1] = w0_.y; acc_[2] = w0_.z; acc_[3] = w0_.w;       \
    acc_[4] = w1_.x; acc_[5] = w1_.y; acc_[6] = w1_.z; acc_[7] = w1_.w;       \
    acc_[8] = w2_.x; acc_[9] = w2_.y; acc_[10] = w2_.z; acc_[11] = w2_.w;     \
    acc_[12] = w3_.x; acc_[13] = w3_.y; acc_[14] = w3_.z; acc_[15] = w3_.w;   \
} while (0)

#define EPI(acc_, cb_) do {                                                   \
    float tmin_ = acc_[0];                                                    \
    _Pragma("unroll")                                                         \
    for (int r_ = 1; r_ < 16; ++r_) tmin_ = fminf(tmin_, acc_[r_]);           \
    tmin_ = fminf(tmin_, __shfl_xor(tmin_, 32, 64));                          \
    mn = fminf(mn, tmin_);                                                    \
    unsigned km_ = 0u;                                                        \
    _Pragma("unroll")                                                         \
    for (int r_ = 0; r_ < 16; ++r_)                                           \
        if (acc_[r_] <= mn + thrR) km_ |= 1u << r_;                           \
    if (__any(km_ != 0u)) {                                                   \
        int kc_ = __popc(km_);                                                \
        int pk_ = __shfl_xor(kc_, 32, 64);                                    \
        int tot_ = kc_ + pk_;                                                 \
        if (tot_ > 0) {                                                       \
            int pfx_ = hi ? pk_ : 0;                                          \
            int o_ = 0;                                                       \
            _Pragma("unroll")                                                 \
            for (int r_ = 0; r_ < 16; ++r_)                                   \
                if (km_ & (1u << r_)) {                                       \
                    int pos_ = cnt_reg + pfx_ + o_;                           \
                    if (pos_ < SLOTS)                                         \
                        cand[(size_t)tok * SLOTS + pos_] =                    \
                            pack_cand(acc_[r_],                               \
                                      (cb_) + (r_ & 3) + 8 * (r_ >> 2) + 4 * hi); \
                    ++o_;                                                     \
                }                                                             \
            cnt_reg += tot_;                                                  \
        }                                                                     \
    }                                                                         \
} while (0)

    for (int st = 0; st < 8; ++st) {
        const int cb0 = st * 128;

#pragma unroll
        for (int pr = 0; pr < 2; ++pr) {
            const int tA = pr * 2, tB = pr * 2 + 1;
            const int cbA = cb0 + tA * 32;
            const int cbB = cb0 + tB * 32;

            f32x16 accA, accB;
            ACC_INIT(accA, cbA);
            ACC_INIT(accB, cbB);

#pragma unroll
            for (int kg = 0; kg < 16; ++kg) {
                short8 wfA = *reinterpret_cast<const short8*>(
                    &wlds[(tA * 16 + kg) * 512 + lane * 8]);
                accA = __builtin_amdgcn_mfma_f32_32x32x16_bf16(wfA, z16[kg], accA, 0, 0, 0);
                short8 wfB = *reinterpret_cast<const short8*>(
                    &wlds[(tB * 16 + kg) * 512 + lane * 8]);
                accB = __builtin_amdgcn_mfma_f32_32x32x16_bf16(wfB, z16[kg], accB, 0, 0, 0);
            }

            EPI(accA, cbA);
            EPI(accB, cbB);
        }

        // re-stage next 128 codes (single buffer: all waves done reading)
        if (st < 7) {
            asm volatile("s_waitcnt lgkmcnt(0)" ::: "memory");
            __builtin_amdgcn_s_barrier();
#pragma unroll
            for (int p = 0; p < 16; ++p) {
                int s = wv_ * 16 + p;
                gl_lds16(wb + (size_t)((st + 1) * 64 + s) * 512 + lane * 8,
                         &wlds[s * 512]);
            }
            asm volatile("s_waitcnt vmcnt(0) lgkmcnt(0)" ::: "memory");
            __builtin_amdgcn_s_barrier();
        }
    }

    // final per-token candidate counts (partner lanes agree; hi==0 writes)
    if (hi == 0) cnt[tok] = (unsigned)cnt_reg;

#undef ACC_INIT
#undef EPI
}

// Exact fp32 refine: wave-parallel prune on packed (q,code), then exact
// evaluation of survivors; fused gather of z_q and counts histogram.
__global__ __launch_bounds__(256) void vq_refine(const float* __restrict__ z,
                                                 const float* __restrict__ w,
                                                 const float* __restrict__ wnorm,
                                                 const float* __restrict__ wmaxp,
                                                 const unsigned* __restrict__ cnt,
                                                 const unsigned* __restrict__ cand,
                                                 int* __restrict__ counts,
                                                 float* __restrict__ out) {
    const int lane = threadIdx.x & 63;
    const int t = blockIdx.x * 4 + (threadIdx.x >> 6);
    float4 zv = reinterpret_cast<const float4*>(z + (size_t)t * ED)[lane];
    unsigned n = cnt[t];
    float bs = 3.4e38f;
    int bj = NE;

    if (n >= 1u && n <= (unsigned)SLOTS) {
        unsigned pk = 0xFFFFFFFFu;
        if (lane < (int)n) pk = cand[(size_t)t * SLOTS + lane];
        unsigned pmin = pk;
#pragma unroll
        for (int m = 1; m < 64; m <<= 1) {
            unsigned o = __shfl_xor(pmin, m, 64);
            pmin = o < pmin ? o : pmin;
        }
        // same thr formula as score; margin covers 2 quantization steps
        float zn = zv.x * zv.x + zv.y * zv.y + zv.z * zv.z + zv.w * zv.w;
#pragma unroll
        for (int m = 1; m < 64; m <<= 1) zn += __shfl_xor(zn, m, 64);
        float thr = THR_REL * sqrtf(zn) * wmaxp[0] + THR_ABS;
        unsigned margin = (unsigned)(16.f * thr) + 2u;
        unsigned qmin = pmin >> 16;
        bool keep = (lane < (int)n) && ((pk >> 16) <= qmin + margin);
        unsigned long long mask = __ballot(keep);
        while (mask) {
            int c = __ffsll(mask) - 1;
            mask &= mask - 1;
            int j = (int)(__shfl(pk, c, 64) & 0xFFFFu);
            float4 wv = reinterpret_cast<const float4*>(w + (size_t)j * ED)[lane];
            float d = fmaf(zv.x, wv.x, fmaf(zv.y, wv.y, fmaf(zv.z, wv.z, zv.w * wv.w)));
#pragma unroll
            for (int m = 1; m < 64; m <<= 1) d += __shfl_xor(d, m, 64);
            float s = fmaf(-2.f, d, wnorm[j]);
            if (s < bs || (s == bs && j < bj)) { bs = s; bj = j; }
        }
    } else {
        // overflow (or impossible empty): exact scan of all codes
        for (int j = 0; j < NE; ++j) {
            float4 wv = reinterpret_cast<const float4*>(w + (size_t)j * ED)[lane];
            float d = fmaf(zv.x, wv.x, fmaf(zv.y, wv.y, fmaf(zv.z, wv.z, zv.w * wv.w)));
#pragma unroll
            for (int m = 1; m < 64; m <<= 1) d += __shfl_xor(d, m, 64);
            float s = fmaf(-2.f, d, wnorm[j]);
            if (s < bs || (s == bs && j < bj)) { bs = s; bj = j; }
        }
    }
    float4 bw = reinterpret_cast<const float4*>(w + (size_t)bj * ED)[lane];
    reinterpret_cast<float4*>(out + (size_t)t * ED)[lane] = bw;
    if (lane == 0) atomicAdd(&counts[bj], 1);
}

__global__ __launch_bounds__(1024) void vq_pplx(const int* __restrict__ counts,
                                                float* __restrict__ out) {
    __shared__ float red[16];
    int tid = threadIdx.x;
    float e = (float)counts[tid] * (1.0f / (float)NT);
    float t = -e * logf(e + 1e-10f);
#pragma unroll
    for (int m = 32; m >= 1; m >>= 1) t += __shfl_down(t, m, 64);
    if ((tid & 63) == 0) red[tid >> 6] = t;
    __syncthreads();
    if (tid < 16) {
        float s = red[tid];
#pragma unroll
        for (int m = 8; m >= 1; m >>= 1) s += __shfl_down(s, m, 16);
        if (tid == 0) out[(size_t)NT * ED] = expf(s);
    }
}

// ======================= fallback (round-1, fp32 VALU) =======================
#define TM 64
#define TN 64
#define KC 64

__global__ __launch_bounds__(256) void vq_prep0(const float* __restrict__ w,
                                                float* __restrict__ wnorm,
                                                int* __restrict__ counts) {
    int c = blockIdx.x * blockDim.x + threadIdx.x;
    if (c < NE) {
        const float4* row = reinterpret_cast<const float4*>(w + (size_t)c * ED);
        float s = 0.f;
#pragma unroll 8
        for (int i = 0; i < ED / 4; ++i) {
            float4 v = row[i];
            s += v.x * v.x + v.y * v.y + v.z * v.z + v.w * v.w;
        }
        wnorm[c] = s;
        counts[c] = 0;
    }
}

__global__ __launch_bounds__(256) void vq_argmin0(const float* __restrict__ z,
                                                  const float* __restrict__ w,
                                                  const float* __restrict__ wnorm,
                                                  int* __restrict__ idx_out,
                                                  int* __restrict__ counts) {
    __shared__ float zs[ED][TM];
    __shared__ float wsh[KC][TN];
    const int tid  = threadIdx.x;
    const int row0 = blockIdx.x * TM;
    const int cg   = tid & 15;
    const int tg   = tid >> 4;
#pragma unroll
    for (int p = 0; p < 16; ++p) {
        int f = p * 256 + tid;
        int k = f >> 4;
        int g = f & 15;
        float4 v;
        v.x = z[(size_t)(row0 + g * 4 + 0) * ED + k];
        v.y = z[(size_t)(row0 + g * 4 + 1) * ED + k];
        v.z = z[(size_t)(row0 + g * 4 + 2) * ED + k];
        v.w = z[(size_t)(row0 + g * 4 + 3) * ED + k];
        *reinterpret_cast<float4*>(&zs[k][g * 4]) = v;
    }
    float best[4];
    int   bidx[4];
#pragma unroll
    for (int i = 0; i < 4; ++i) { best[i] = 3.4e38f; bidx[i] = 0; }
    for (int ct = 0; ct < NE / TN; ++ct) {
        const int c0 = ct * TN;
        float acc[4][4];
#pragma unroll
        for (int i = 0; i < 4; ++i)
#pragma unroll
            for (int j = 0; j < 4; ++j) acc[i][j] = 0.f;
        for (int kc = 0; kc < ED / KC; ++kc) {
            __syncthreads();
#pragma unroll
            for (int p = 0; p < 4; ++p) {
                int f = p * 256 + tid;
                int k = f >> 4;
                int g = f & 15;
                float4 v;
                v.x = w[(size_t)(c0 + g * 4 + 0) * ED + kc * KC + k];
                v.y = w[(size_t)(c0 + g * 4 + 1) * ED + kc * KC + k];
                v.z = w[(size_t)(c0 + g * 4 + 2) * ED + kc * KC + k];
                v.w = w[(size_t)(c0 + g * 4 + 3) * ED + kc * KC + k];
                *reinterpret_cast<float4*>(&wsh[k][g * 4]) = v;
            }
            __syncthreads();
#pragma unroll 8
            for (int k = 0; k < KC; ++k) {
                float4 zv = *reinterpret_cast<const float4*>(&zs[kc * KC + k][tg * 4]);
                float4 wv = *reinterpret_cast<const float4*>(&wsh[k][cg * 4]);
                float zr[4] = { zv.x, zv.y, zv.z, zv.w };
                float wr[4] = { wv.x, wv.y, wv.z, wv.w };
#pragma unroll
                for (int i = 0; i < 4; ++i)
#pragma unroll
                    for (int j = 0; j < 4; ++j)
                        acc[i][j] = fmaf(zr[i], wr[j], acc[i][j]);
            }
        }
#pragma unroll
        for (int j = 0; j < 4; ++j) {
            int c = c0 + cg * 4 + j;
            float wn = wnorm[c];
#pragma unroll
            for (int i = 0; i < 4; ++i) {
                float s = fmaf(-2.f, acc[i][j], wn);
                if (s < best[i]) { best[i] = s; bidx[i] = c; }
            }
        }
    }
#pragma unroll
    for (int m = 1; m < 16; m <<= 1) {
#pragma unroll
        for (int i = 0; i < 4; ++i) {
            float ov = __shfl_xor(best[i], m, 64);
            int   oi = __shfl_xor(bidx[i], m, 64);
            if (ov < best[i] || (ov == best[i] && oi < bidx[i])) {
                best[i] = ov; bidx[i] = oi;
            }
        }
    }
    if (cg == 0) {
#pragma unroll
        for (int i = 0; i < 4; ++i) {
            int t = row0 + tg * 4 + i;
            idx_out[t] = bidx[i];
            atomicAdd(&counts[bidx[i]], 1);
        }
    }
}

__global__ __launch_bounds__(256) void vq_gather0(const float* __restrict__ w,
                                                  const int* __restrict__ idx,
                                                  float* __restrict__ out) {
    int tid = threadIdx.x;
    int t   = blockIdx.x * 4 + (tid >> 6);
    int c4  = tid & 63;
    int id  = idx[t];
    float4 v = reinterpret_cast<const float4*>(w + (size_t)id * ED)[c4];
    reinterpret_cast<float4*>(out + (size_t)t * ED)[c4] = v;
}
// ============================================================================

extern "C" void kernel_launch(void* const* d_in, const int* in_sizes, int n_in,
                              void* d_out, int out_size, void* d_ws, size_t ws_size,
                              hipStream_t stream) {
    const float* z = (const float*)d_in[0];
    const float* w = (const float*)d_in[1];
    float* out = (float*)d_out;
    char* ws = (char*)d_ws;

    float*          wnorm  = (float*)ws;
    int*            counts = (int*)(ws + 4096);
    float*          wmax   = (float*)(ws + 8192);
    unsigned short* wb     = (unsigned short*)(ws + 8448);
    unsigned*       cnt    = (unsigned*)(ws + 532736);
    unsigned*       cand   = (unsigned*)(ws + 1057024);
    const size_t need = 1057024 + (size_t)NT * SLOTS * 4;

    if (ws_size >= need) {
        vq_prep<<<4, 256, 0, stream>>>(w, wnorm, counts, wb);
        vq_wmax<<<1, 1024, 0, stream>>>(wnorm, wmax);
        vq_score6<<<NT / 128, 256, 0, stream>>>(z, wb, wnorm, wmax, cnt, cand);
        vq_refine<<<NT / 4, 256, 0, stream>>>(z, w, wnorm, wmax, cnt, cand, counts, out);
        vq_pplx<<<1, 1024, 0, stream>>>(counts, out);
    } else {
        int* idxw = (int*)(ws + 8192);
        vq_prep0<<<(NE + 255) / 256, 256, 0, stream>>>(w, wnorm, counts);
        vq_argmin0<<<NT / TM, 256, 0, stream>>>(z, w, wnorm, idxw, counts);
        vq_gather0<<<NT / 4, 256, 0, stream>>>(w, idxw, out);
        vq_pplx<<<1, 1024, 0, stream>>>(counts, out);
    }
}

// Round 14
// 281.938 us; speedup vs baseline: 1.2635x; 1.0610x over previous
//
#include <hip/hip_runtime.h>
#include <math.h>

#define NE   1024
#define ED   256
#define NT   131072
#define SLOTS 32

// provable bf16-RNE score-error bound: |s~ - s| <= 2*(2^-8+2^-8+2^-16)*|z||w| + eps
#define THR_REL 0.016f
#define THR_ABS 0.02f

typedef __attribute__((ext_vector_type(8))) short short8;
typedef __attribute__((ext_vector_type(4))) float f32x4;

__device__ inline unsigned short f2bf(float f) {
    unsigned u = __float_as_uint(f);
    unsigned r = (u + 0x7FFFu + ((u >> 16) & 1u)) >> 16;   // RNE
    return (unsigned short)r;
}

__device__ inline void gl_lds16(const void* g, void* l) {
    __builtin_amdgcn_global_load_lds(
        (const __attribute__((address_space(1))) unsigned int*)g,
        (__attribute__((address_space(3))) unsigned int*)l, 16, 0, 0);
}

// packed candidate: (q(s~) << 16) | code ; q monotone in s~ so u32-min is
// lexicographic (s~, code)-min. q = floor((s + 1024) * 16), clamped.
__device__ inline unsigned pack_cand(float s, int code) {
    float qf = (s + 1024.f) * 16.f;
    int q = (int)qf;
    q = q < 0 ? 0 : (q > 65535 ? 65535 : q);
    return ((unsigned)q << 16) | (unsigned)code;
}

// ---------------------------------------------------------------------------
// ws layout:
//   0        wnorm  f32[1024]
//   4096     counts int[1024]
//   8192     wmax   f32[1]
//   8448     wb     bf16[1024*256]    (512 KB) — rows prescaled by -2 (exact)
//   532736   cnt    u32[131072]       (512 KB) — low 8: count, high 24: margin
//   1057024  cand   u32[131072*32]    (16 MB)   need = 17834240
// ---------------------------------------------------------------------------

__global__ __launch_bounds__(256) void vq_prep(const float* __restrict__ w,
                                               float* __restrict__ wnorm,
                                               int* __restrict__ counts,
                                               unsigned short* __restrict__ wb) {
    int c = blockIdx.x * 256 + threadIdx.x;
    if (c < NE) {
        const float4* row = reinterpret_cast<const float4*>(w + (size_t)c * ED);
        ushort4* wbr = reinterpret_cast<ushort4*>(wb + (size_t)c * ED);
        float s = 0.f;
#pragma unroll 8
        for (int i = 0; i < ED / 4; ++i) {
            float4 v = row[i];
            s += v.x * v.x + v.y * v.y + v.z * v.z + v.w * v.w;
            ushort4 o;   // prescale by -2 (exact power-of-2 scaling, RNE commutes)
            o.x = f2bf(-2.f * v.x); o.y = f2bf(-2.f * v.y);
            o.z = f2bf(-2.f * v.z); o.w = f2bf(-2.f * v.w);
            wbr[i] = o;
        }
        wnorm[c] = s;
        counts[c] = 0;
    }
}

__global__ __launch_bounds__(1024) void vq_wmax(const float* __restrict__ wnorm,
                                                float* __restrict__ wmax) {
    __shared__ float red[16];
    int tid = threadIdx.x;
    float v = wnorm[tid];
#pragma unroll
    for (int m = 32; m >= 1; m >>= 1) v = fmaxf(v, __shfl_xor(v, m, 64));
    if ((tid & 63) == 0) red[tid >> 6] = v;
    __syncthreads();
    if (tid == 0) {
        float m = red[0];
#pragma unroll
        for (int i = 1; i < 16; ++i) m = fmaxf(m, red[i]);
        wmax[0] = sqrtf(m);
    }
}

// W-stationary score kernel (r11 shell), swapped MFMA operands:
// C[row=code][col=token]. 1024 blocks x 256 threads (4 waves x 32 tokens),
// 16 stages of 64 codes through 32 KB LDS. wb prescaled by -2 and acc
// INITIALIZED from wnorm -> accumulator IS the score after the K loop
// (no epilogue fma). cnt packs {count, margin} so refine can prune
// without reading z.
__global__ __launch_bounds__(256) void vq_score7(const float* __restrict__ z,
                                                 const unsigned short* __restrict__ wb,
                                                 const float* __restrict__ wnorm,
                                                 const float* __restrict__ wmaxp,
                                                 unsigned* __restrict__ cnt,
                                                 unsigned* __restrict__ cand) {
    __shared__ __align__(16) unsigned short wlds[16384];   // 32 KB
    __shared__ float wn_lds[NE];                           // 4 KB
    __shared__ float thr_lds[4][32];                       // 0.5 KB

    const int tid  = threadIdx.x;
    const int lane = tid & 63;
    const int wv_  = tid >> 6;          // 0..3
    const int l15  = lane & 15;
    const int l4   = lane >> 4;
    const int row0 = blockIdx.x * 128 + wv_ * 32;

    // ---- issue stage 0 FIRST so it overlaps the z-load/A-prep below ----
    // 32 frags of 1 KB (s = nj*8+kg, nj<4); wave wv_ stages s = wv_*8+p
#pragma unroll
    for (int p = 0; p < 8; ++p) {
        int s  = wv_ * 8 + p;
        int nj = s >> 3, kg = s & 7;
        int j  = nj * 16 + l15;                          // stage 0
        gl_lds16(wb + (size_t)j * ED + kg * 32 + l4 * 8, &wlds[s * 512]);
    }

    // wnorm -> LDS (256 threads x float4)
    reinterpret_cast<float4*>(wn_lds)[tid] = reinterpret_cast<const float4*>(wnorm)[tid];

    // ---- Z fragments: B-operand layout (col=token=l15, k=kg*32+l4*8+i) ----
    short8 a[2][8];
    float zn2[2];
#pragma unroll
    for (int mi = 0; mi < 2; ++mi) {
        const float* zr = z + (size_t)(row0 + mi * 16 + l15) * ED;
        float s = 0.f;
#pragma unroll
        for (int kg = 0; kg < 8; ++kg) {
            int k0 = kg * 32 + l4 * 8;
            float4 p = *reinterpret_cast<const float4*>(zr + k0);
            float4 q = *reinterpret_cast<const float4*>(zr + k0 + 4);
            s += p.x * p.x + p.y * p.y + p.z * p.z + p.w * p.w
               + q.x * q.x + q.y * q.y + q.z * q.z + q.w * q.w;
            short8 t;
            t[0] = (short)f2bf(p.x); t[1] = (short)f2bf(p.y);
            t[2] = (short)f2bf(p.z); t[3] = (short)f2bf(p.w);
            t[4] = (short)f2bf(q.x); t[5] = (short)f2bf(q.y);
            t[6] = (short)f2bf(q.z); t[7] = (short)f2bf(q.w);
            a[mi][kg] = t;
        }
        zn2[mi] = s;
    }
#pragma unroll
    for (int mi = 0; mi < 2; ++mi) {
        zn2[mi] += __shfl_xor(zn2[mi], 16, 64);
        zn2[mi] += __shfl_xor(zn2[mi], 32, 64);
    }
    float wmax = wmaxp[0];
#pragma unroll
    for (int mi = 0; mi < 2; ++mi)
        thr_lds[wv_][mi * 16 + l15] = THR_REL * sqrtf(zn2[mi]) * wmax + THR_ABS;

    asm volatile("s_waitcnt vmcnt(0) lgkmcnt(0)" ::: "memory");
    __builtin_amdgcn_s_barrier();

    // per-token (token = l15 + 16*mi) threshold / running min / count
    float thrR[2], mn[2];
    int cnt_reg[2];
#pragma unroll
    for (int mi = 0; mi < 2; ++mi) {
        thrR[mi] = thr_lds[wv_][mi * 16 + l15];
        mn[mi] = 3.4e38f;
        cnt_reg[mi] = 0;
    }

    for (int st = 0; st < 16; ++st) {
        const int c0 = st * 64;

        for (int base = 0; base < 4; base += 2) {   // 2 batches of 2 tiles
            // acc init from wnorm (same float4 for both mi; codes on rows)
            f32x4 acc[2][2];   // [tb][mi]
#pragma unroll
            for (int tb = 0; tb < 2; ++tb) {
                float4 wnv = *reinterpret_cast<const float4*>(
                    &wn_lds[c0 + (base + tb) * 16 + l4 * 4]);
                acc[tb][0] = {wnv.x, wnv.y, wnv.z, wnv.w};
                acc[tb][1] = {wnv.x, wnv.y, wnv.z, wnv.w};
            }

#pragma unroll
            for (int tb = 0; tb < 2; ++tb)
#pragma unroll
                for (int kg = 0; kg < 8; ++kg) {
                    short8 wf = *reinterpret_cast<const short8*>(
                        &wlds[(((base + tb) * 8 + kg) * 512) + lane * 8]);
                    // swapped: A = codes (-2W), B = tokens (Z)
                    acc[tb][0] = __builtin_amdgcn_mfma_f32_16x16x32_bf16(wf, a[0][kg], acc[tb][0], 0, 0, 0);
                    acc[tb][1] = __builtin_amdgcn_mfma_f32_16x16x32_bf16(wf, a[1][kg], acc[tb][1], 0, 0, 0);
                }

            // acc IS the score; in-thread min per token
            float tmin[2] = {3.4e38f, 3.4e38f};
#pragma unroll
            for (int tb = 0; tb < 2; ++tb)
#pragma unroll
                for (int mi = 0; mi < 2; ++mi)
#pragma unroll
                    for (int r = 0; r < 4; ++r)
                        tmin[mi] = fminf(tmin[mi], acc[tb][mi][r]);
            // cross-l4 reduce (2 shuffles), fold into running min
#pragma unroll
            for (int mi = 0; mi < 2; ++mi) {
                float v = tmin[mi];
                v = fminf(v, __shfl_xor(v, 16, 64));
                v = fminf(v, __shfl_xor(v, 32, 64));
                mn[mi] = fminf(mn[mi], v);
            }

            // keep masks: bit tb*4+r
            unsigned km[2] = {0u, 0u};
#pragma unroll
            for (int tb = 0; tb < 2; ++tb)
#pragma unroll
                for (int mi = 0; mi < 2; ++mi)
#pragma unroll
                    for (int r = 0; r < 4; ++r)
                        if (acc[tb][mi][r] <= mn[mi] + thrR[mi])
                            km[mi] |= 1u << (tb * 4 + r);

            if (__any((km[0] | km[1]) != 0u)) {
#pragma unroll
                for (int mi = 0; mi < 2; ++mi) {
                    int kc = __popc(km[mi]);
                    int b = __shfl_xor(kc, 16, 64);   // l4 ^ 1
                    int c = __shfl_xor(kc, 32, 64);   // l4 ^ 2
                    int d = __shfl_xor(b, 32, 64);    // l4 ^ 3
                    int tot = kc + b + c + d;
                    if (tot > 0) {
                        int pfx = (l4 == 1) ? b
                                : (l4 == 2) ? (c + d)
                                : (l4 == 3) ? (b + c + d) : 0;
                        int tok = row0 + mi * 16 + l15;
                        int o = 0;
#pragma unroll
                        for (int tb = 0; tb < 2; ++tb)
#pragma unroll
                            for (int r = 0; r < 4; ++r)
                                if (km[mi] & (1u << (tb * 4 + r))) {
                                    int pos = cnt_reg[mi] + pfx + o;
                                    if (pos < SLOTS)
                                        cand[(size_t)tok * SLOTS + pos] =
                                            pack_cand(acc[tb][mi][r],
                                                      c0 + (base + tb) * 16 + l4 * 4 + r);
                                    ++o;
                                }
                        cnt_reg[mi] += tot;
                    }
                }
            }
        }

        // re-stage next 64 codes (single buffer: all waves done reading)
        if (st < 15) {
            asm volatile("s_waitcnt lgkmcnt(0)" ::: "memory");
            __builtin_amdgcn_s_barrier();
#pragma unroll
            for (int p = 0; p < 8; ++p) {
                int s  = wv_ * 8 + p;
                int nj = s >> 3, kg = s & 7;
                int j  = (st + 1) * 64 + nj * 16 + l15;
                gl_lds16(wb + (size_t)j * ED + kg * 32 + l4 * 8, &wlds[s * 512]);
            }
            asm volatile("s_waitcnt vmcnt(0) lgkmcnt(0)" ::: "memory");
            __builtin_amdgcn_s_barrier();
        }
    }

    // final per-token {count, margin} (4 l4-lanes agree; l4==0 writes)
    if (l4 == 0) {
#pragma unroll
        for (int mi = 0; mi < 2; ++mi) {
            unsigned n = (unsigned)cnt_reg[mi];
            if (n > 255u) n = 255u;
            unsigned marg = (unsigned)(16.f * thrR[mi]) + 2u;
            cnt[row0 + mi * 16 + l15] = n | (marg << 8);
        }
    }
}

// Exact fp32 refine, prune-FIRST: margin comes packed in cnt, so the prune
// runs before any z access. Sole survivor == exact argmin (superset
// invariant) -> direct gather, NO z read. Multi-survivor/overflow -> exact
// fp32 evaluation as before.
__global__ __launch_bounds__(256) void vq_refine(const float* __restrict__ z,
                                                 const float* __restrict__ w,
                                                 const float* __restrict__ wnorm,
                                                 const unsigned* __restrict__ cnt,
                                                 const unsigned* __restrict__ cand,
                                                 int* __restrict__ counts,
                                                 float* __restrict__ out) {
    const int lane = threadIdx.x & 63;
    const int t = blockIdx.x * 4 + (threadIdx.x >> 6);

    const unsigned tpack = cnt[t];
    const unsigned n     = tpack & 0xFFu;
    const unsigned margin = tpack >> 8;

    int bj = NE;
    bool need_exact = true;
    unsigned pk = 0xFFFFFFFFu;
    unsigned long long mask = 0ull;

    if (n >= 1u && n <= (unsigned)SLOTS) {
        if (lane < (int)n) pk = cand[(size_t)t * SLOTS + lane];
        unsigned pmin = pk;
#pragma unroll
        for (int m = 1; m < 64; m <<= 1) {
            unsigned o = __shfl_xor(pmin, m, 64);
            pmin = o < pmin ? o : pmin;
        }
        unsigned qmin = pmin >> 16;
        bool keep = (lane < (int)n) && ((pk >> 16) <= qmin + margin);
        mask = __ballot(keep);
        if (__popcll(mask) == 1) {
            int c = __ffsll(mask) - 1;
            bj = (int)(__shfl(pk, c, 64) & 0xFFFFu);
            need_exact = false;          // sole survivor == exact argmin
        }
    }

    if (need_exact) {
        float4 zv = reinterpret_cast<const float4*>(z + (size_t)t * ED)[lane];
        float bs = 3.4e38f;
        bj = NE;
        if (n >= 1u && n <= (unsigned)SLOTS) {
            unsigned long long m2 = mask;
            while (m2) {
                int c = __ffsll(m2) - 1;
                m2 &= m2 - 1;
                int j = (int)(__shfl(pk, c, 64) & 0xFFFFu);
                float4 wv = reinterpret_cast<const float4*>(w + (size_t)j * ED)[lane];
                float d = fmaf(zv.x, wv.x, fmaf(zv.y, wv.y, fmaf(zv.z, wv.z, zv.w * wv.w)));
#pragma unroll
                for (int m = 1; m < 64; m <<= 1) d += __shfl_xor(d, m, 64);
                float s = fmaf(-2.f, d, wnorm[j]);
                if (s < bs || (s == bs && j < bj)) { bs = s; bj = j; }
            }
        } else {
            // overflow (or impossible empty): exact scan of all codes
            for (int j = 0; j < NE; ++j) {
                float4 wv = reinterpret_cast<const float4*>(w + (size_t)j * ED)[lane];
                float d = fmaf(zv.x, wv.x, fmaf(zv.y, wv.y, fmaf(zv.z, wv.z, zv.w * wv.w)));
#pragma unroll
                for (int m = 1; m < 64; m <<= 1) d += __shfl_xor(d, m, 64);
                float s = fmaf(-2.f, d, wnorm[j]);
                if (s < bs || (s == bs && j < bj)) { bs = s; bj = j; }
            }
        }
    }

    float4 bw = reinterpret_cast<const float4*>(w + (size_t)bj * ED)[lane];
    reinterpret_cast<float4*>(out + (size_t)t * ED)[lane] = bw;
    if (lane == 0) atomicAdd(&counts[bj], 1);
}

__global__ __launch_bounds__(1024) void vq_pplx(const int* __restrict__ counts,
                                                float* __restrict__ out) {
    __shared__ float red[16];
    int tid = threadIdx.x;
    float e = (float)counts[tid] * (1.0f / (float)NT);
    float t = -e * logf(e + 1e-10f);
#pragma unroll
    for (int m = 32; m >= 1; m >>= 1) t += __shfl_down(t, m, 64);
    if ((tid & 63) == 0) red[tid >> 6] = t;
    __syncthreads();
    if (tid < 16) {
        float s = red[tid];
#pragma unroll
        for (int m = 8; m >= 1; m >>= 1) s += __shfl_down(s, m, 16);
        if (tid == 0) out[(size_t)NT * ED] = expf(s);
    }
}

// ======================= fallback (round-1, fp32 VALU) =======================
#define TM 64
#define TN 64
#define KC 64

__global__ __launch_bounds__(256) void vq_prep0(const float* __restrict__ w,
                                                float* __restrict__ wnorm,
                                                int* __restrict__ counts) {
    int c = blockIdx.x * blockDim.x + threadIdx.x;
    if (c < NE) {
        const float4* row = reinterpret_cast<const float4*>(w + (size_t)c * ED);
        float s = 0.f;
#pragma unroll 8
        for (int i = 0; i < ED / 4; ++i) {
            float4 v = row[i];
            s += v.x * v.x + v.y * v.y + v.z * v.z + v.w * v.w;
        }
        wnorm[c] = s;
        counts[c] = 0;
    }
}

__global__ __launch_bounds__(256) void vq_argmin0(const float* __restrict__ z,
                                                  const float* __restrict__ w,
                                                  const float* __restrict__ wnorm,
                                                  int* __restrict__ idx_out,
                                                  int* __restrict__ counts) {
    __shared__ float zs[ED][TM];
    __shared__ float wsh[KC][TN];
    const int tid  = threadIdx.x;
    const int row0 = blockIdx.x * TM;
    const int cg   = tid & 15;
    const int tg   = tid >> 4;
#pragma unroll
    for (int p = 0; p < 16; ++p) {
        int f = p * 256 + tid;
        int k = f >> 4;
        int g = f & 15;
        float4 v;
        v.x = z[(size_t)(row0 + g * 4 + 0) * ED + k];
        v.y = z[(size_t)(row0 + g * 4 + 1) * ED + k];
        v.z = z[(size_t)(row0 + g * 4 + 2) * ED + k];
        v.w = z[(size_t)(row0 + g * 4 + 3) * ED + k];
        *reinterpret_cast<float4*>(&zs[k][g * 4]) = v;
    }
    float best[4];
    int   bidx[4];
#pragma unroll
    for (int i = 0; i < 4; ++i) { best[i] = 3.4e38f; bidx[i] = 0; }
    for (int ct = 0; ct < NE / TN; ++ct) {
        const int c0 = ct * TN;
        float acc[4][4];
#pragma unroll
        for (int i = 0; i < 4; ++i)
#pragma unroll
            for (int j = 0; j < 4; ++j) acc[i][j] = 0.f;
        for (int kc = 0; kc < ED / KC; ++kc) {
            __syncthreads();
#pragma unroll
            for (int p = 0; p < 4; ++p) {
                int f = p * 256 + tid;
                int k = f >> 4;
                int g = f & 15;
                float4 v;
                v.x = w[(size_t)(c0 + g * 4 + 0) * ED + kc * KC + k];
                v.y = w[(size_t)(c0 + g * 4 + 1) * ED + kc * KC + k];
                v.z = w[(size_t)(c0 + g * 4 + 2) * ED + kc * KC + k];
                v.w = w[(size_t)(c0 + g * 4 + 3) * ED + kc * KC + k];
                *reinterpret_cast<float4*>(&wsh[k][g * 4]) = v;
            }
            __syncthreads();
#pragma unroll 8
            for (int k = 0; k < KC; ++k) {
                float4 zv = *reinterpret_cast<const float4*>(&zs[kc * KC + k][tg * 4]);
                float4 wv = *reinterpret_cast<const float4*>(&wsh[k][cg * 4]);
                float zr[4] = { zv.x, zv.y, zv.z, zv.w };
                float wr[4] = { wv.x, wv.y, wv.z, wv.w };
#pragma unroll
                for (int i = 0; i < 4; ++i)
#pragma unroll
                    for (int j = 0; j < 4; ++j)
                        acc[i][j] = fmaf(zr[i], wr[j], acc[i][j]);
            }
        }
#pragma unroll
        for (int j = 0; j < 4; ++j) {
            int c = c0 + cg * 4 + j;
            float wn = wnorm[c];
#pragma unroll
            for (int i = 0; i < 4; ++i) {
                float s = fmaf(-2.f, acc[i][j], wn);
                if (s < best[i]) { best[i] = s; bidx[i] = c; }
            }
        }
    }
#pragma unroll
    for (int m = 1; m < 16; m <<= 1) {
#pragma unroll
        for (int i = 0; i < 4; ++i) {
            float ov = __shfl_xor(best[i], m, 64);
            int   oi = __shfl_xor(bidx[i], m, 64);
            if (ov < best[i] || (ov == best[i] && oi < bidx[i])) {
                best[i] = ov; bidx[i] = oi;
            }
        }
    }
    if (cg == 0) {
#pragma unroll
        for (int i = 0; i < 4; ++i) {
            int t = row0 + tg * 4 + i;
            idx_out[t] = bidx[i];
            atomicAdd(&counts[bidx[i]], 1);
        }
    }
}

__global__ __launch_bounds__(256) void vq_gather0(const float* __restrict__ w,
                                                  const int* __restrict__ idx,
                                                  float* __restrict__ out) {
    int tid = threadIdx.x;
    int t   = blockIdx.x * 4 + (tid >> 6);
    int c4  = tid & 63;
    int id  = idx[t];
    float4 v = reinterpret_cast<const float4*>(w + (size_t)id * ED)[c4];
    reinterpret_cast<float4*>(out + (size_t)t * ED)[c4] = v;
}
// ============================================================================

extern "C" void kernel_launch(void* const* d_in, const int* in_sizes, int n_in,
                              void* d_out, int out_size, void* d_ws, size_t ws_size,
                              hipStream_t stream) {
    const float* z = (const float*)d_in[0];
    const float* w = (const float*)d_in[1];
    float* out = (float*)d_out;
    char* ws = (char*)d_ws;

    float*          wnorm  = (float*)ws;
    int*            counts = (int*)(ws + 4096);
    float*          wmax   = (float*)(ws + 8192);
    unsigned short* wb     = (unsigned short*)(ws + 8448);
    unsigned*       cnt    = (unsigned*)(ws + 532736);
    unsigned*       cand   = (unsigned*)(ws + 1057024);
    const size_t need = 1057024 + (size_t)NT * SLOTS * 4;

    if (ws_size >= need) {
        vq_prep<<<4, 256, 0, stream>>>(w, wnorm, counts, wb);
        vq_wmax<<<1, 1024, 0, stream>>>(wnorm, wmax);
        vq_score7<<<NT / 128, 256, 0, stream>>>(z, wb, wnorm, wmax, cnt, cand);
        vq_refine<<<NT / 4, 256, 0, stream>>>(z, w, wnorm, cnt, cand, counts, out);
        vq_pplx<<<1, 1024, 0, stream>>>(counts, out);
    } else {
        int* idxw = (int*)(ws + 8192);
        vq_prep0<<<(NE + 255) / 256, 256, 0, stream>>>(w, wnorm, counts);
        vq_argmin0<<<NT / TM, 256, 0, stream>>>(z, w, wnorm, idxw, counts);
        vq_gather0<<<NT / 4, 256, 0, stream>>>(w, idxw, out);
        vq_pplx<<<1, 1024, 0, stream>>>(counts, out);
    }
}

// Round 15
// 275.683 us; speedup vs baseline: 1.2921x; 1.0227x over previous
//
#include <hip/hip_runtime.h>
#include <math.h>

#define NE   1024
#define ED   256
#define NT   131072
#define SLOTS 32

// provable bf16-RNE score-error bound: |s~ - s| <= 2*(2^-8+2^-8+2^-16)*|z||w| + eps
#define THR_REL 0.016f
#define THR_ABS 0.02f

typedef __attribute__((ext_vector_type(8))) short short8;
typedef __attribute__((ext_vector_type(4))) float f32x4;

__device__ inline unsigned short f2bf(float f) {
    unsigned u = __float_as_uint(f);
    unsigned r = (u + 0x7FFFu + ((u >> 16) & 1u)) >> 16;   // RNE
    return (unsigned short)r;
}

__device__ inline void gl_lds16(const void* g, void* l) {
    __builtin_amdgcn_global_load_lds(
        (const __attribute__((address_space(1))) unsigned int*)g,
        (__attribute__((address_space(3))) unsigned int*)l, 16, 0, 0);
}

// packed candidate: (q(s~) << 16) | code ; q monotone in s~ so u32-min is
// lexicographic (s~, code)-min. q = floor((s + 1024) * 16), clamped.
__device__ inline unsigned pack_cand(float s, int code) {
    float qf = (s + 1024.f) * 16.f;
    int q = (int)qf;
    q = q < 0 ? 0 : (q > 65535 ? 65535 : q);
    return ((unsigned)q << 16) | (unsigned)code;
}

// ---------------------------------------------------------------------------
// ws layout:
//   0        wnorm  f32[1024]
//   4096     counts int[1024]
//   8192     wmax   f32[1]
//   8448     wb     bf16[1024*256]    (512 KB) — rows prescaled by -2 (exact)
//   532736   cnt    u32[131072]       (512 KB) — low 8: count, high 24: margin
//   1057024  cand   u32[131072*32]    (16 MB)   need = 17834240
// ---------------------------------------------------------------------------

__global__ __launch_bounds__(256) void vq_prep(const float* __restrict__ w,
                                               float* __restrict__ wnorm,
                                               int* __restrict__ counts,
                                               unsigned short* __restrict__ wb) {
    int c = blockIdx.x * 256 + threadIdx.x;
    if (c < NE) {
        const float4* row = reinterpret_cast<const float4*>(w + (size_t)c * ED);
        ushort4* wbr = reinterpret_cast<ushort4*>(wb + (size_t)c * ED);
        float s = 0.f;
#pragma unroll 8
        for (int i = 0; i < ED / 4; ++i) {
            float4 v = row[i];
            s += v.x * v.x + v.y * v.y + v.z * v.z + v.w * v.w;
            ushort4 o;   // prescale by -2 (exact power-of-2 scaling, RNE commutes)
            o.x = f2bf(-2.f * v.x); o.y = f2bf(-2.f * v.y);
            o.z = f2bf(-2.f * v.z); o.w = f2bf(-2.f * v.w);
            wbr[i] = o;
        }
        wnorm[c] = s;
        counts[c] = 0;
    }
}

__global__ __launch_bounds__(1024) void vq_wmax(const float* __restrict__ wnorm,
                                                float* __restrict__ wmax) {
    __shared__ float red[16];
    int tid = threadIdx.x;
    float v = wnorm[tid];
#pragma unroll
    for (int m = 32; m >= 1; m >>= 1) v = fmaxf(v, __shfl_xor(v, m, 64));
    if ((tid & 63) == 0) red[tid >> 6] = v;
    __syncthreads();
    if (tid == 0) {
        float m = red[0];
#pragma unroll
        for (int i = 1; i < 16; ++i) m = fmaxf(m, red[i]);
        wmax[0] = sqrtf(m);
    }
}

// W-stationary score kernel (r14 arithmetic), NOW with T4 counted-vmcnt
// double-buffered staging: 2 x 32 KB LDS buffers; stage(st+2) issued after
// the read-release barrier; loop-top wait is vmcnt(8) (my 8 newest in-flight
// loads = stage st+2) -> stage st proven complete WITHOUT draining the
// pipeline. wb prescaled by -2, acc initialized from wnorm (acc IS score).
__global__ __launch_bounds__(256) void vq_score8(const float* __restrict__ z,
                                                 const unsigned short* __restrict__ wb,
                                                 const float* __restrict__ wnorm,
                                                 const float* __restrict__ wmaxp,
                                                 unsigned* __restrict__ cnt,
                                                 unsigned* __restrict__ cand) {
    __shared__ __align__(16) unsigned short wlds[2][16384]; // 2 x 32 KB
    __shared__ float wn_lds[NE];                            // 4 KB
    __shared__ float thr_lds[4][32];                        // 0.5 KB

    const int tid  = threadIdx.x;
    const int lane = tid & 63;
    const int wv_  = tid >> 6;          // 0..3
    const int l15  = lane & 15;
    const int l4   = lane >> 4;
    const int row0 = blockIdx.x * 128 + wv_ * 32;

    // ---- prologue: issue stage 0 -> buf0 and stage 1 -> buf1 FIRST ----
    // (A-prep's z loads below are newer; the compiler's waits for z data
    //  drain these too — one-time cost, overlapped with the z loads.)
#pragma unroll
    for (int p = 0; p < 8; ++p) {
        int s  = wv_ * 8 + p;
        int nj = s >> 3, kg = s & 7;
        gl_lds16(wb + (size_t)(nj * 16 + l15) * ED + kg * 32 + l4 * 8,
                 &wlds[0][s * 512]);
    }
#pragma unroll
    for (int p = 0; p < 8; ++p) {
        int s  = wv_ * 8 + p;
        int nj = s >> 3, kg = s & 7;
        gl_lds16(wb + (size_t)(64 + nj * 16 + l15) * ED + kg * 32 + l4 * 8,
                 &wlds[1][s * 512]);
    }

    // wnorm -> LDS (256 threads x float4)
    reinterpret_cast<float4*>(wn_lds)[tid] = reinterpret_cast<const float4*>(wnorm)[tid];

    // ---- Z fragments: B-operand layout (col=token=l15, k=kg*32+l4*8+i) ----
    short8 a[2][8];
    float zn2[2];
#pragma unroll
    for (int mi = 0; mi < 2; ++mi) {
        const float* zr = z + (size_t)(row0 + mi * 16 + l15) * ED;
        float s = 0.f;
#pragma unroll
        for (int kg = 0; kg < 8; ++kg) {
            int k0 = kg * 32 + l4 * 8;
            float4 p = *reinterpret_cast<const float4*>(zr + k0);
            float4 q = *reinterpret_cast<const float4*>(zr + k0 + 4);
            s += p.x * p.x + p.y * p.y + p.z * p.z + p.w * p.w
               + q.x * q.x + q.y * q.y + q.z * q.z + q.w * q.w;
            short8 t;
            t[0] = (short)f2bf(p.x); t[1] = (short)f2bf(p.y);
            t[2] = (short)f2bf(p.z); t[3] = (short)f2bf(p.w);
            t[4] = (short)f2bf(q.x); t[5] = (short)f2bf(q.y);
            t[6] = (short)f2bf(q.z); t[7] = (short)f2bf(q.w);
            a[mi][kg] = t;
        }
        zn2[mi] = s;
    }
#pragma unroll
    for (int mi = 0; mi < 2; ++mi) {
        zn2[mi] += __shfl_xor(zn2[mi], 16, 64);
        zn2[mi] += __shfl_xor(zn2[mi], 32, 64);
    }
    float wmax = wmaxp[0];
#pragma unroll
    for (int mi = 0; mi < 2; ++mi)
        thr_lds[wv_][mi * 16 + l15] = THR_REL * sqrtf(zn2[mi]) * wmax + THR_ABS;

    asm volatile("s_waitcnt vmcnt(0) lgkmcnt(0)" ::: "memory");
    __builtin_amdgcn_s_barrier();

    // per-token (token = l15 + 16*mi) threshold / running min / count
    float thrR[2], mn[2];
    int cnt_reg[2];
#pragma unroll
    for (int mi = 0; mi < 2; ++mi) {
        thrR[mi] = thr_lds[wv_][mi * 16 + l15];
        mn[mi] = 3.4e38f;
        cnt_reg[mi] = 0;
    }

    for (int st = 0; st < 16; ++st) {
        const int b  = st & 1;
        const int c0 = st * 64;

        // stage(st) complete?  The 8 newest outstanding VMEM ops are
        // stage(st+2)'s loads (issued at the bottom of iteration st-? ...
        // actually stage(st+1)'s during prologue for st=0); counted wait
        // keeps them in flight. Last iteration has nothing newer -> 0.
        if (st < 15) {
            asm volatile("s_waitcnt vmcnt(8)" ::: "memory");
        } else {
            asm volatile("s_waitcnt vmcnt(0)" ::: "memory");
        }
        __builtin_amdgcn_s_barrier();   // all waves' stage(st) done

        for (int base = 0; base < 4; base += 2) {   // 2 batches of 2 tiles
            // acc init from wnorm (same float4 for both mi; codes on rows)
            f32x4 acc[2][2];   // [tb][mi]
#pragma unroll
            for (int tb = 0; tb < 2; ++tb) {
                float4 wnv = *reinterpret_cast<const float4*>(
                    &wn_lds[c0 + (base + tb) * 16 + l4 * 4]);
                acc[tb][0] = {wnv.x, wnv.y, wnv.z, wnv.w};
                acc[tb][1] = {wnv.x, wnv.y, wnv.z, wnv.w};
            }

#pragma unroll
            for (int tb = 0; tb < 2; ++tb)
#pragma unroll
                for (int kg = 0; kg < 8; ++kg) {
                    short8 wf = *reinterpret_cast<const short8*>(
                        &wlds[b][(((base + tb) * 8 + kg) * 512) + lane * 8]);
                    // swapped: A = codes (-2W), B = tokens (Z)
                    acc[tb][0] = __builtin_amdgcn_mfma_f32_16x16x32_bf16(wf, a[0][kg], acc[tb][0], 0, 0, 0);
                    acc[tb][1] = __builtin_amdgcn_mfma_f32_16x16x32_bf16(wf, a[1][kg], acc[tb][1], 0, 0, 0);
                }

            // acc IS the score; in-thread min per token
            float tmin[2] = {3.4e38f, 3.4e38f};
#pragma unroll
            for (int tb = 0; tb < 2; ++tb)
#pragma unroll
                for (int mi = 0; mi < 2; ++mi)
#pragma unroll
                    for (int r = 0; r < 4; ++r)
                        tmin[mi] = fminf(tmin[mi], acc[tb][mi][r]);
            // cross-l4 reduce (2 shuffles), fold into running min
#pragma unroll
            for (int mi = 0; mi < 2; ++mi) {
                float v = tmin[mi];
                v = fminf(v, __shfl_xor(v, 16, 64));
                v = fminf(v, __shfl_xor(v, 32, 64));
                mn[mi] = fminf(mn[mi], v);
            }

            // keep masks: bit tb*4+r
            unsigned km[2] = {0u, 0u};
#pragma unroll
            for (int tb = 0; tb < 2; ++tb)
#pragma unroll
                for (int mi = 0; mi < 2; ++mi)
#pragma unroll
                    for (int r = 0; r < 4; ++r)
                        if (acc[tb][mi][r] <= mn[mi] + thrR[mi])
                            km[mi] |= 1u << (tb * 4 + r);

            if (__any((km[0] | km[1]) != 0u)) {
#pragma unroll
                for (int mi = 0; mi < 2; ++mi) {
                    int kc = __popc(km[mi]);
                    int b2 = __shfl_xor(kc, 16, 64);   // l4 ^ 1
                    int c2 = __shfl_xor(kc, 32, 64);   // l4 ^ 2
                    int d2 = __shfl_xor(b2, 32, 64);   // l4 ^ 3
                    int tot = kc + b2 + c2 + d2;
                    if (tot > 0) {
                        int pfx = (l4 == 1) ? b2
                                : (l4 == 2) ? (c2 + d2)
                                : (l4 == 3) ? (b2 + c2 + d2) : 0;
                        int tok = row0 + mi * 16 + l15;
                        int o = 0;
#pragma unroll
                        for (int tb = 0; tb < 2; ++tb)
#pragma unroll
                            for (int r = 0; r < 4; ++r)
                                if (km[mi] & (1u << (tb * 4 + r))) {
                                    int pos = cnt_reg[mi] + pfx + o;
                                    if (pos < SLOTS)
                                        cand[(size_t)tok * SLOTS + pos] =
                                            pack_cand(acc[tb][mi][r],
                                                      c0 + (base + tb) * 16 + l4 * 4 + r);
                                    ++o;
                                }
                        cnt_reg[mi] += tot;
                    }
                }
            }
        }

        // release buf[b] (all waves done reading), then issue stage(st+2)
        // into it — these 8 loads stay in flight across the next loop-top
        // vmcnt(8) wait (covered by compute(st+1)).
        asm volatile("s_waitcnt lgkmcnt(0)" ::: "memory");
        __builtin_amdgcn_s_barrier();
        if (st + 2 < 16) {
            const int cN = (st + 2) * 64;
#pragma unroll
            for (int p = 0; p < 8; ++p) {
                int s  = wv_ * 8 + p;
                int nj = s >> 3, kg = s & 7;
                gl_lds16(wb + (size_t)(cN + nj * 16 + l15) * ED + kg * 32 + l4 * 8,
                         &wlds[b][s * 512]);
            }
        }
    }

    // final per-token {count, margin} (4 l4-lanes agree; l4==0 writes)
    if (l4 == 0) {
#pragma unroll
        for (int mi = 0; mi < 2; ++mi) {
            unsigned n = (unsigned)cnt_reg[mi];
            if (n > 255u) n = 255u;
            unsigned marg = (unsigned)(16.f * thrR[mi]) + 2u;
            cnt[row0 + mi * 16 + l15] = n | (marg << 8);
        }
    }
}

// Exact fp32 refine, prune-FIRST: margin comes packed in cnt, so the prune
// runs before any z access. Sole survivor == exact argmin (superset
// invariant) -> direct gather, NO z read. Multi-survivor/overflow -> exact
// fp32 evaluation as before.
__global__ __launch_bounds__(256) void vq_refine(const float* __restrict__ z,
                                                 const float* __restrict__ w,
                                                 const float* __restrict__ wnorm,
                                                 const unsigned* __restrict__ cnt,
                                                 const unsigned* __restrict__ cand,
                                                 int* __restrict__ counts,
                                                 float* __restrict__ out) {
    const int lane = threadIdx.x & 63;
    const int t = blockIdx.x * 4 + (threadIdx.x >> 6);

    const unsigned tpack = cnt[t];
    const unsigned n     = tpack & 0xFFu;
    const unsigned margin = tpack >> 8;

    int bj = NE;
    bool need_exact = true;
    unsigned pk = 0xFFFFFFFFu;
    unsigned long long mask = 0ull;

    if (n >= 1u && n <= (unsigned)SLOTS) {
        if (lane < (int)n) pk = cand[(size_t)t * SLOTS + lane];
        unsigned pmin = pk;
#pragma unroll
        for (int m = 1; m < 64; m <<= 1) {
            unsigned o = __shfl_xor(pmin, m, 64);
            pmin = o < pmin ? o : pmin;
        }
        unsigned qmin = pmin >> 16;
        bool keep = (lane < (int)n) && ((pk >> 16) <= qmin + margin);
        mask = __ballot(keep);
        if (__popcll(mask) == 1) {
            int c = __ffsll(mask) - 1;
            bj = (int)(__shfl(pk, c, 64) & 0xFFFFu);
            need_exact = false;          // sole survivor == exact argmin
        }
    }

    if (need_exact) {
        float4 zv = reinterpret_cast<const float4*>(z + (size_t)t * ED)[lane];
        float bs = 3.4e38f;
        bj = NE;
        if (n >= 1u && n <= (unsigned)SLOTS) {
            unsigned long long m2 = mask;
            while (m2) {
                int c = __ffsll(m2) - 1;
                m2 &= m2 - 1;
                int j = (int)(__shfl(pk, c, 64) & 0xFFFFu);
                float4 wv = reinterpret_cast<const float4*>(w + (size_t)j * ED)[lane];
                float d = fmaf(zv.x, wv.x, fmaf(zv.y, wv.y, fmaf(zv.z, wv.z, zv.w * wv.w)));
#pragma unroll
                for (int m = 1; m < 64; m <<= 1) d += __shfl_xor(d, m, 64);
                float s = fmaf(-2.f, d, wnorm[j]);
                if (s < bs || (s == bs && j < bj)) { bs = s; bj = j; }
            }
        } else {
            // overflow (or impossible empty): exact scan of all codes
            for (int j = 0; j < NE; ++j) {
                float4 wv = reinterpret_cast<const float4*>(w + (size_t)j * ED)[lane];
                float d = fmaf(zv.x, wv.x, fmaf(zv.y, wv.y, fmaf(zv.z, wv.z, zv.w * wv.w)));
#pragma unroll
                for (int m = 1; m < 64; m <<= 1) d += __shfl_xor(d, m, 64);
                float s = fmaf(-2.f, d, wnorm[j]);
                if (s < bs || (s == bs && j < bj)) { bs = s; bj = j; }
            }
        }
    }

    float4 bw = reinterpret_cast<const float4*>(w + (size_t)bj * ED)[lane];
    reinterpret_cast<float4*>(out + (size_t)t * ED)[lane] = bw;
    if (lane == 0) atomicAdd(&counts[bj], 1);
}

__global__ __launch_bounds__(1024) void vq_pplx(const int* __restrict__ counts,
                                                float* __restrict__ out) {
    __shared__ float red[16];
    int tid = threadIdx.x;
    float e = (float)counts[tid] * (1.0f / (float)NT);
    float t = -e * logf(e + 1e-10f);
#pragma unroll
    for (int m = 32; m >= 1; m >>= 1) t += __shfl_down(t, m, 64);
    if ((tid & 63) == 0) red[tid >> 6] = t;
    __syncthreads();
    if (tid < 16) {
        float s = red[tid];
#pragma unroll
        for (int m = 8; m >= 1; m >>= 1) s += __shfl_down(s, m, 16);
        if (tid == 0) out[(size_t)NT * ED] = expf(s);
    }
}

// ======================= fallback (round-1, fp32 VALU) =======================
#define TM 64
#define TN 64
#define KC 64

__global__ __launch_bounds__(256) void vq_prep0(const float* __restrict__ w,
                                                float* __restrict__ wnorm,
                                                int* __restrict__ counts) {
    int c = blockIdx.x * blockDim.x + threadIdx.x;
    if (c < NE) {
        const float4* row = reinterpret_cast<const float4*>(w + (size_t)c * ED);
        float s = 0.f;
#pragma unroll 8
        for (int i = 0; i < ED / 4; ++i) {
            float4 v = row[i];
            s += v.x * v.x + v.y * v.y + v.z * v.z + v.w * v.w;
        }
        wnorm[c] = s;
        counts[c] = 0;
    }
}

__global__ __launch_bounds__(256) void vq_argmin0(const float* __restrict__ z,
                                                  const float* __restrict__ w,
                                                  const float* __restrict__ wnorm,
                                                  int* __restrict__ idx_out,
                                                  int* __restrict__ counts) {
    __shared__ float zs[ED][TM];
    __shared__ float wsh[KC][TN];
    const int tid  = threadIdx.x;
    const int row0 = blockIdx.x * TM;
    const int cg   = tid & 15;
    const int tg   = tid >> 4;
#pragma unroll
    for (int p = 0; p < 16; ++p) {
        int f = p * 256 + tid;
        int k = f >> 4;
        int g = f & 15;
        float4 v;
        v.x = z[(size_t)(row0 + g * 4 + 0) * ED + k];
        v.y = z[(size_t)(row0 + g * 4 + 1) * ED + k];
        v.z = z[(size_t)(row0 + g * 4 + 2) * ED + k];
        v.w = z[(size_t)(row0 + g * 4 + 3) * ED + k];
        *reinterpret_cast<float4*>(&zs[k][g * 4]) = v;
    }
    float best[4];
    int   bidx[4];
#pragma unroll
    for (int i = 0; i < 4; ++i) { best[i] = 3.4e38f; bidx[i] = 0; }
    for (int ct = 0; ct < NE / TN; ++ct) {
        const int c0 = ct * TN;
        float acc[4][4];
#pragma unroll
        for (int i = 0; i < 4; ++i)
#pragma unroll
            for (int j = 0; j < 4; ++j) acc[i][j] = 0.f;
        for (int kc = 0; kc < ED / KC; ++kc) {
            __syncthreads();
#pragma unroll
            for (int p = 0; p < 4; ++p) {
                int f = p * 256 + tid;
                int k = f >> 4;
                int g = f & 15;
                float4 v;
                v.x = w[(size_t)(c0 + g * 4 + 0) * ED + kc * KC + k];
                v.y = w[(size_t)(c0 + g * 4 + 1) * ED + kc * KC + k];
                v.z = w[(size_t)(c0 + g * 4 + 2) * ED + kc * KC + k];
                v.w = w[(size_t)(c0 + g * 4 + 3) * ED + kc * KC + k];
                *reinterpret_cast<float4*>(&wsh[k][g * 4]) = v;
            }
            __syncthreads();
#pragma unroll 8
            for (int k = 0; k < KC; ++k) {
                float4 zv = *reinterpret_cast<const float4*>(&zs[kc * KC + k][tg * 4]);
                float4 wv = *reinterpret_cast<const float4*>(&wsh[k][cg * 4]);
                float zr[4] = { zv.x, zv.y, zv.z, zv.w };
                float wr[4] = { wv.x, wv.y, wv.z, wv.w };
#pragma unroll
                for (int i = 0; i < 4; ++i)
#pragma unroll
                    for (int j = 0; j < 4; ++j)
                        acc[i][j] = fmaf(zr[i], wr[j], acc[i][j]);
            }
        }
#pragma unroll
        for (int j = 0; j < 4; ++j) {
            int c = c0 + cg * 4 + j;
            float wn = wnorm[c];
#pragma unroll
            for (int i = 0; i < 4; ++i) {
                float s = fmaf(-2.f, acc[i][j], wn);
                if (s < best[i]) { best[i] = s; bidx[i] = c; }
            }
        }
    }
#pragma unroll
    for (int m = 1; m < 16; m <<= 1) {
#pragma unroll
        for (int i = 0; i < 4; ++i) {
            float ov = __shfl_xor(best[i], m, 64);
            int   oi = __shfl_xor(bidx[i], m, 64);
            if (ov < best[i] || (ov == best[i] && oi < bidx[i])) {
                best[i] = ov; bidx[i] = oi;
            }
        }
    }
    if (cg == 0) {
#pragma unroll
        for (int i = 0; i < 4; ++i) {
            int t = row0 + tg * 4 + i;
            idx_out[t] = bidx[i];
            atomicAdd(&counts[bidx[i]], 1);
        }
    }
}

__global__ __launch_bounds__(256) void vq_gather0(const float* __restrict__ w,
                                                  const int* __restrict__ idx,
                                                  float* __restrict__ out) {
    int tid = threadIdx.x;
    int t   = blockIdx.x * 4 + (tid >> 6);
    int c4  = tid & 63;
    int id  = idx[t];
    float4 v = reinterpret_cast<const float4*>(w + (size_t)id * ED)[c4];
    reinterpret_cast<float4*>(out + (size_t)t * ED)[c4] = v;
}
// ============================================================================

extern "C" void kernel_launch(void* const* d_in, const int* in_sizes, int n_in,
                              void* d_out, int out_size, void* d_ws, size_t ws_size,
                              hipStream_t stream) {
    const float* z = (const float*)d_in[0];
    const float* w = (const float*)d_in[1];
    float* out = (float*)d_out;
    char* ws = (char*)d_ws;

    float*          wnorm  = (float*)ws;
    int*            counts = (int*)(ws + 4096);
    float*          wmax   = (float*)(ws + 8192);
    unsigned short* wb     = (unsigned short*)(ws + 8448);
    unsigned*       cnt    = (unsigned*)(ws + 532736);
    unsigned*       cand   = (unsigned*)(ws + 1057024);
    const size_t need = 1057024 + (size_t)NT * SLOTS * 4;

    if (ws_size >= need) {
        vq_prep<<<4, 256, 0, stream>>>(w, wnorm, counts, wb);
        vq_wmax<<<1, 1024, 0, stream>>>(wnorm, wmax);
        vq_score8<<<NT / 128, 256, 0, stream>>>(z, wb, wnorm, wmax, cnt, cand);
        vq_refine<<<NT / 4, 256, 0, stream>>>(z, w, wnorm, cnt, cand, counts, out);
        vq_pplx<<<1, 1024, 0, stream>>>(counts, out);
    } else {
        int* idxw = (int*)(ws + 8192);
        vq_prep0<<<(NE + 255) / 256, 256, 0, stream>>>(w, wnorm, counts);
        vq_argmin0<<<NT / TM, 256, 0, stream>>>(z, w, wnorm, idxw, counts);
        vq_gather0<<<NT / 4, 256, 0, stream>>>(w, idxw, out);
        vq_pplx<<<1, 1024, 0, stream>>>(counts, out);
    }
}

// Round 16
// 260.343 us; speedup vs baseline: 1.3683x; 1.0589x over previous
//
#include <hip/hip_runtime.h>
#include <math.h>

#define NE   1024
#define ED   256
#define NT   131072
#define SLOTS 32

#define THR_REL 0.016f
#define THR_ABS 0.02f

typedef __attribute__((ext_vector_type(8))) short short8;
typedef __attribute__((ext_vector_type(4))) float f32x4;

__device__ inline unsigned short f2bf(float f) {
    unsigned u = __float_as_uint(f);
    unsigned r = (u + 0x7FFFu + ((u >> 16) & 1u)) >> 16;   // RNE
    return (unsigned short)r;
}

__device__ inline void gl_lds16(const void* g, void* l) {
    __builtin_amdgcn_global_load_lds(
        (const __attribute__((address_space(1))) unsigned int*)g,
        (__attribute__((address_space(3))) unsigned int*)l, 16, 0, 0);
}

// packed candidate: (q(s~) << 16) | code ; q monotone in s~ so u32-min is
// lexicographic (s~, code)-min. q = floor((s + 1024) * 16), clamped.
__device__ inline unsigned pack_cand(float s, int code) {
    float qf = (s + 1024.f) * 16.f;
    int q = (int)qf;
    q = q < 0 ? 0 : (q > 65535 ? 65535 : q);
    return ((unsigned)q << 16) | (unsigned)code;
}

// ---------------------------------------------------------------------------
// ws layout:
//   0        wnorm  f32[1024]
//   4096     counts int[1024]
//   8192     wmaxsq f32[1]             (zero-init by hipMemsetAsync; atomicMax)
//   8448     wb     bf16[1024*256]    (512 KB) — rows prescaled by -2 (exact)
//   532736   cnt    u32[131072]       (512 KB) — low 8: count, high 24: margin
//   1057024  cand   u32[131072*32]    (16 MB)   need = 17834240
// ---------------------------------------------------------------------------

__global__ __launch_bounds__(256) void vq_prep(const float* __restrict__ w,
                                               float* __restrict__ wnorm,
                                               int* __restrict__ counts,
                                               unsigned short* __restrict__ wb,
                                               unsigned* __restrict__ wmaxsq) {
    int c = blockIdx.x * 256 + threadIdx.x;
    if (c < NE) {
        const float4* row = reinterpret_cast<const float4*>(w + (size_t)c * ED);
        ushort4* wbr = reinterpret_cast<ushort4*>(wb + (size_t)c * ED);
        float s = 0.f;
#pragma unroll 8
        for (int i = 0; i < ED / 4; ++i) {
            float4 v = row[i];
            s += v.x * v.x + v.y * v.y + v.z * v.z + v.w * v.w;
            ushort4 o;   // prescale by -2 (exact power-of-2 scaling, RNE commutes)
            o.x = f2bf(-2.f * v.x); o.y = f2bf(-2.f * v.y);
            o.z = f2bf(-2.f * v.z); o.w = f2bf(-2.f * v.w);
            wbr[i] = o;
        }
        wnorm[c] = s;
        counts[c] = 0;
        // positive-float bits are monotone as unsigned -> atomicMax works
        atomicMax(wmaxsq, __float_as_uint(s));
    }
}

// W-stationary score kernel: r15's counted-vmcnt 2-deep double buffer, now
// with a single 64-MFMA cluster per stage (8 indep chains) wrapped in
// s_setprio, and ONE epilogue per 64 codes (half the cross-lane ops).
// wb prescaled by -2, acc initialized from wnorm -> acc IS the score.
__global__ __launch_bounds__(256) void vq_score9(const float* __restrict__ z,
                                                 const unsigned short* __restrict__ wb,
                                                 const float* __restrict__ wnorm,
                                                 const unsigned* __restrict__ wmaxsq,
                                                 unsigned* __restrict__ cnt,
                                                 unsigned* __restrict__ cand) {
    __shared__ __align__(16) unsigned short wlds[2][16384]; // 2 x 32 KB
    __shared__ float wn_lds[NE];                            // 4 KB

    const int tid  = threadIdx.x;
    const int lane = tid & 63;
    const int wv_  = tid >> 6;          // 0..3
    const int l15  = lane & 15;
    const int l4   = lane >> 4;
    const int row0 = blockIdx.x * 128 + wv_ * 32;

    // ---- prologue: issue stage 0 -> buf0 and stage 1 -> buf1 FIRST ----
#pragma unroll
    for (int p = 0; p < 8; ++p) {
        int s  = wv_ * 8 + p;
        int nj = s >> 3, kg = s & 7;
        gl_lds16(wb + (size_t)(nj * 16 + l15) * ED + kg * 32 + l4 * 8,
                 &wlds[0][s * 512]);
    }
#pragma unroll
    for (int p = 0; p < 8; ++p) {
        int s  = wv_ * 8 + p;
        int nj = s >> 3, kg = s & 7;
        gl_lds16(wb + (size_t)(64 + nj * 16 + l15) * ED + kg * 32 + l4 * 8,
                 &wlds[1][s * 512]);
    }

    // wnorm -> LDS (256 threads x float4)
    reinterpret_cast<float4*>(wn_lds)[tid] = reinterpret_cast<const float4*>(wnorm)[tid];

    // ---- Z fragments: B-operand layout (col=token=l15, k=kg*32+l4*8+i) ----
    short8 a[2][8];
    float thrR[2], mn[2];
    int cnt_reg[2];
    {
        float wmax = sqrtf(__uint_as_float(wmaxsq[0]));
#pragma unroll
        for (int mi = 0; mi < 2; ++mi) {
            const float* zr = z + (size_t)(row0 + mi * 16 + l15) * ED;
            float s = 0.f;
#pragma unroll
            for (int kg = 0; kg < 8; ++kg) {
                int k0 = kg * 32 + l4 * 8;
                float4 p = *reinterpret_cast<const float4*>(zr + k0);
                float4 q = *reinterpret_cast<const float4*>(zr + k0 + 4);
                s += p.x * p.x + p.y * p.y + p.z * p.z + p.w * p.w
                   + q.x * q.x + q.y * q.y + q.z * q.z + q.w * q.w;
                short8 t;
                t[0] = (short)f2bf(p.x); t[1] = (short)f2bf(p.y);
                t[2] = (short)f2bf(p.z); t[3] = (short)f2bf(p.w);
                t[4] = (short)f2bf(q.x); t[5] = (short)f2bf(q.y);
                t[6] = (short)f2bf(q.z); t[7] = (short)f2bf(q.w);
                a[mi][kg] = t;
            }
            s += __shfl_xor(s, 16, 64);
            s += __shfl_xor(s, 32, 64);
            thrR[mi] = THR_REL * sqrtf(s) * wmax + THR_ABS;
            mn[mi] = 3.4e38f;
            cnt_reg[mi] = 0;
        }
    }

    asm volatile("s_waitcnt vmcnt(0) lgkmcnt(0)" ::: "memory");
    __builtin_amdgcn_s_barrier();

    for (int st = 0; st < 16; ++st) {
        const int b  = st & 1;
        const int c0 = st * 64;

        // stage(st) proven complete while stage(st+2)'s 8 loads stay in flight
        if (st < 15) {
            asm volatile("s_waitcnt vmcnt(8)" ::: "memory");
        } else {
            asm volatile("s_waitcnt vmcnt(0)" ::: "memory");
        }
        __builtin_amdgcn_s_barrier();

        // ---- acc init from wnorm (4 tiles x 2 mi; codes on rows) ----
        f32x4 acc0A, acc0B, acc1A, acc1B, acc2A, acc2B, acc3A, acc3B;
        {
            float4 w0 = *reinterpret_cast<const float4*>(&wn_lds[c0 + 0 * 16 + l4 * 4]);
            float4 w1 = *reinterpret_cast<const float4*>(&wn_lds[c0 + 1 * 16 + l4 * 4]);
            float4 w2 = *reinterpret_cast<const float4*>(&wn_lds[c0 + 2 * 16 + l4 * 4]);
            float4 w3 = *reinterpret_cast<const float4*>(&wn_lds[c0 + 3 * 16 + l4 * 4]);
            acc0A = {w0.x, w0.y, w0.z, w0.w}; acc0B = acc0A;
            acc1A = {w1.x, w1.y, w1.z, w1.w}; acc1B = acc1A;
            acc2A = {w2.x, w2.y, w2.z, w2.w}; acc2B = acc2A;
            acc3A = {w3.x, w3.y, w3.z, w3.w}; acc3B = acc3A;
        }

        // ---- single 64-MFMA cluster, 8 independent chains ----
        __builtin_amdgcn_s_setprio(1);
#pragma unroll
        for (int kg = 0; kg < 8; ++kg) {
            short8 wf0 = *reinterpret_cast<const short8*>(
                &wlds[b][((0 * 8 + kg) * 512) + lane * 8]);
            acc0A = __builtin_amdgcn_mfma_f32_16x16x32_bf16(wf0, a[0][kg], acc0A, 0, 0, 0);
            acc0B = __builtin_amdgcn_mfma_f32_16x16x32_bf16(wf0, a[1][kg], acc0B, 0, 0, 0);
            short8 wf1 = *reinterpret_cast<const short8*>(
                &wlds[b][((1 * 8 + kg) * 512) + lane * 8]);
            acc1A = __builtin_amdgcn_mfma_f32_16x16x32_bf16(wf1, a[0][kg], acc1A, 0, 0, 0);
            acc1B = __builtin_amdgcn_mfma_f32_16x16x32_bf16(wf1, a[1][kg], acc1B, 0, 0, 0);
            short8 wf2 = *reinterpret_cast<const short8*>(
                &wlds[b][((2 * 8 + kg) * 512) + lane * 8]);
            acc2A = __builtin_amdgcn_mfma_f32_16x16x32_bf16(wf2, a[0][kg], acc2A, 0, 0, 0);
            acc2B = __builtin_amdgcn_mfma_f32_16x16x32_bf16(wf2, a[1][kg], acc2B, 0, 0, 0);
            short8 wf3 = *reinterpret_cast<const short8*>(
                &wlds[b][((3 * 8 + kg) * 512) + lane * 8]);
            acc3A = __builtin_amdgcn_mfma_f32_16x16x32_bf16(wf3, a[0][kg], acc3A, 0, 0, 0);
            acc3B = __builtin_amdgcn_mfma_f32_16x16x32_bf16(wf3, a[1][kg], acc3B, 0, 0, 0);
        }
        __builtin_amdgcn_s_setprio(0);

        // ---- ONE epilogue over all 64 codes ----
        // in-thread min per token (16 values per mi)
        float tmin[2];
        {
            f32x4 m0 = acc0A, m1 = acc1A;
#pragma unroll
            for (int r = 0; r < 4; ++r) {
                m0[r] = fminf(m0[r], acc2A[r]);
                m1[r] = fminf(m1[r], acc3A[r]);
            }
            float v = fminf(fminf(m0[0], m0[1]), fminf(m0[2], m0[3]));
            v = fminf(v, fminf(fminf(m1[0], m1[1]), fminf(m1[2], m1[3])));
            tmin[0] = v;
            f32x4 n0 = acc0B, n1 = acc1B;
#pragma unroll
            for (int r = 0; r < 4; ++r) {
                n0[r] = fminf(n0[r], acc2B[r]);
                n1[r] = fminf(n1[r], acc3B[r]);
            }
            float u = fminf(fminf(n0[0], n0[1]), fminf(n0[2], n0[3]));
            u = fminf(u, fminf(fminf(n1[0], n1[1]), fminf(n1[2], n1[3])));
            tmin[1] = u;
        }
#pragma unroll
        for (int mi = 0; mi < 2; ++mi) {
            float v = tmin[mi];
            v = fminf(v, __shfl_xor(v, 16, 64));
            v = fminf(v, __shfl_xor(v, 32, 64));
            mn[mi] = fminf(mn[mi], v);
        }

        // keep masks: bit t*4+r (t = tile 0..3)
        unsigned km[2] = {0u, 0u};
#pragma unroll
        for (int r = 0; r < 4; ++r) {
            if (acc0A[r] <= mn[0] + thrR[0]) km[0] |= 1u << (0 + r);
            if (acc1A[r] <= mn[0] + thrR[0]) km[0] |= 1u << (4 + r);
            if (acc2A[r] <= mn[0] + thrR[0]) km[0] |= 1u << (8 + r);
            if (acc3A[r] <= mn[0] + thrR[0]) km[0] |= 1u << (12 + r);
            if (acc0B[r] <= mn[1] + thrR[1]) km[1] |= 1u << (0 + r);
            if (acc1B[r] <= mn[1] + thrR[1]) km[1] |= 1u << (4 + r);
            if (acc2B[r] <= mn[1] + thrR[1]) km[1] |= 1u << (8 + r);
            if (acc3B[r] <= mn[1] + thrR[1]) km[1] |= 1u << (12 + r);
        }

        if (__any((km[0] | km[1]) != 0u)) {
#pragma unroll
            for (int mi = 0; mi < 2; ++mi) {
                int kc = __popc(km[mi]);
                int b2 = __shfl_xor(kc, 16, 64);   // l4 ^ 1
                int c2 = __shfl_xor(kc, 32, 64);   // l4 ^ 2
                int d2 = __shfl_xor(b2, 32, 64);   // l4 ^ 3
                int tot = kc + b2 + c2 + d2;
                if (tot > 0) {
                    int pfx = (l4 == 1) ? b2
                            : (l4 == 2) ? (c2 + d2)
                            : (l4 == 3) ? (b2 + c2 + d2) : 0;
                    int tok = row0 + mi * 16 + l15;
                    int o = 0;
                    const f32x4* accs[4] = {
                        mi == 0 ? &acc0A : &acc0B,
                        mi == 0 ? &acc1A : &acc1B,
                        mi == 0 ? &acc2A : &acc2B,
                        mi == 0 ? &acc3A : &acc3B };
#pragma unroll
                    for (int t = 0; t < 4; ++t)
#pragma unroll
                        for (int r = 0; r < 4; ++r)
                            if (km[mi] & (1u << (t * 4 + r))) {
                                int pos = cnt_reg[mi] + pfx + o;
                                if (pos < SLOTS)
                                    cand[(size_t)tok * SLOTS + pos] =
                                        pack_cand((*accs[t])[r],
                                                  c0 + t * 16 + l4 * 4 + r);
                                ++o;
                            }
                    cnt_reg[mi] += tot;
                }
            }
        }

        // release buf[b], then issue stage(st+2) into it (stays in flight
        // across the next loop-top vmcnt(8), covered by compute(st+1)).
        asm volatile("s_waitcnt lgkmcnt(0)" ::: "memory");
        __builtin_amdgcn_s_barrier();
        if (st + 2 < 16) {
            const int cN = (st + 2) * 64;
#pragma unroll
            for (int p = 0; p < 8; ++p) {
                int s  = wv_ * 8 + p;
                int nj = s >> 3, kg = s & 7;
                gl_lds16(wb + (size_t)(cN + nj * 16 + l15) * ED + kg * 32 + l4 * 8,
                         &wlds[b][s * 512]);
            }
        }
    }

    // final per-token {count, margin} (4 l4-lanes agree; l4==0 writes)
    if (l4 == 0) {
#pragma unroll
        for (int mi = 0; mi < 2; ++mi) {
            unsigned n = (unsigned)cnt_reg[mi];
            if (n > 255u) n = 255u;
            unsigned marg = (unsigned)(16.f * thrR[mi]) + 2u;
            cnt[row0 + mi * 16 + l15] = n | (marg << 8);
        }
    }
}

// Exact fp32 refine, prune-FIRST: margin comes packed in cnt, so the prune
// runs before any z access. Sole survivor == exact argmin -> direct gather.
__global__ __launch_bounds__(256) void vq_refine(const float* __restrict__ z,
                                                 const float* __restrict__ w,
                                                 const float* __restrict__ wnorm,
                                                 const unsigned* __restrict__ cnt,
                                                 const unsigned* __restrict__ cand,
                                                 int* __restrict__ counts,
                                                 float* __restrict__ out) {
    const int lane = threadIdx.x & 63;
    const int t = blockIdx.x * 4 + (threadIdx.x >> 6);

    const unsigned tpack = cnt[t];
    const unsigned n     = tpack & 0xFFu;
    const unsigned margin = tpack >> 8;

    int bj = NE;
    bool need_exact = true;
    unsigned pk = 0xFFFFFFFFu;
    unsigned long long mask = 0ull;

    if (n >= 1u && n <= (unsigned)SLOTS) {
        if (lane < (int)n) pk = cand[(size_t)t * SLOTS + lane];
        unsigned pmin = pk;
#pragma unroll
        for (int m = 1; m < 64; m <<= 1) {
            unsigned o = __shfl_xor(pmin, m, 64);
            pmin = o < pmin ? o : pmin;
        }
        unsigned qmin = pmin >> 16;
        bool keep = (lane < (int)n) && ((pk >> 16) <= qmin + margin);
        mask = __ballot(keep);
        if (__popcll(mask) == 1) {
            int c = __ffsll(mask) - 1;
            bj = (int)(__shfl(pk, c, 64) & 0xFFFFu);
            need_exact = false;          // sole survivor == exact argmin
        }
    }

    if (need_exact) {
        float4 zv = reinterpret_cast<const float4*>(z + (size_t)t * ED)[lane];
        float bs = 3.4e38f;
        bj = NE;
        if (n >= 1u && n <= (unsigned)SLOTS) {
            unsigned long long m2 = mask;
            while (m2) {
                int c = __ffsll(m2) - 1;
                m2 &= m2 - 1;
                int j = (int)(__shfl(pk, c, 64) & 0xFFFFu);
                float4 wv = reinterpret_cast<const float4*>(w + (size_t)j * ED)[lane];
                float d = fmaf(zv.x, wv.x, fmaf(zv.y, wv.y, fmaf(zv.z, wv.z, zv.w * wv.w)));
#pragma unroll
                for (int m = 1; m < 64; m <<= 1) d += __shfl_xor(d, m, 64);
                float s = fmaf(-2.f, d, wnorm[j]);
                if (s < bs || (s == bs && j < bj)) { bs = s; bj = j; }
            }
        } else {
            for (int j = 0; j < NE; ++j) {
                float4 wv = reinterpret_cast<const float4*>(w + (size_t)j * ED)[lane];
                float d = fmaf(zv.x, wv.x, fmaf(zv.y, wv.y, fmaf(zv.z, wv.z, zv.w * wv.w)));
#pragma unroll
                for (int m = 1; m < 64; m <<= 1) d += __shfl_xor(d, m, 64);
                float s = fmaf(-2.f, d, wnorm[j]);
                if (s < bs || (s == bs && j < bj)) { bs = s; bj = j; }
            }
        }
    }

    float4 bw = reinterpret_cast<const float4*>(w + (size_t)bj * ED)[lane];
    reinterpret_cast<float4*>(out + (size_t)t * ED)[lane] = bw;
    if (lane == 0) atomicAdd(&counts[bj], 1);
}

__global__ __launch_bounds__(1024) void vq_pplx(const int* __restrict__ counts,
                                                float* __restrict__ out) {
    __shared__ float red[16];
    int tid = threadIdx.x;
    float e = (float)counts[tid] * (1.0f / (float)NT);
    float t = -e * logf(e + 1e-10f);
#pragma unroll
    for (int m = 32; m >= 1; m >>= 1) t += __shfl_down(t, m, 64);
    if ((tid & 63) == 0) red[tid >> 6] = t;
    __syncthreads();
    if (tid < 16) {
        float s = red[tid];
#pragma unroll
        for (int m = 8; m >= 1; m >>= 1) s += __shfl_down(s, m, 16);
        if (tid == 0) out[(size_t)NT * ED] = expf(s);
    }
}

// ======================= fallback (round-1, fp32 VALU) =======================
#define TM 64
#define TN 64
#define KC 64

__global__ __launch_bounds__(256) void vq_prep0(const float* __restrict__ w,
                                                float* __restrict__ wnorm,
                                                int* __restrict__ counts) {
    int c = blockIdx.x * blockDim.x + threadIdx.x;
    if (c < NE) {
        const float4* row = reinterpret_cast<const float4*>(w + (size_t)c * ED);
        float s = 0.f;
#pragma unroll 8
        for (int i = 0; i < ED / 4; ++i) {
            float4 v = row[i];
            s += v.x * v.x + v.y * v.y + v.z * v.z + v.w * v.w;
        }
        wnorm[c] = s;
        counts[c] = 0;
    }
}

__global__ __launch_bounds__(256) void vq_argmin0(const float* __restrict__ z,
                                                  const float* __restrict__ w,
                                                  const float* __restrict__ wnorm,
                                                  int* __restrict__ idx_out,
                                                  int* __restrict__ counts) {
    __shared__ float zs[ED][TM];
    __shared__ float wsh[KC][TN];
    const int tid  = threadIdx.x;
    const int row0 = blockIdx.x * TM;
    const int cg   = tid & 15;
    const int tg   = tid >> 4;
#pragma unroll
    for (int p = 0; p < 16; ++p) {
        int f = p * 256 + tid;
        int k = f >> 4;
        int g = f & 15;
        float4 v;
        v.x = z[(size_t)(row0 + g * 4 + 0) * ED + k];
        v.y = z[(size_t)(row0 + g * 4 + 1) * ED + k];
        v.z = z[(size_t)(row0 + g * 4 + 2) * ED + k];
        v.w = z[(size_t)(row0 + g * 4 + 3) * ED + k];
        *reinterpret_cast<float4*>(&zs[k][g * 4]) = v;
    }
    float best[4];
    int   bidx[4];
#pragma unroll
    for (int i = 0; i < 4; ++i) { best[i] = 3.4e38f; bidx[i] = 0; }
    for (int ct = 0; ct < NE / TN; ++ct) {
        const int c0 = ct * TN;
        float acc[4][4];
#pragma unroll
        for (int i = 0; i < 4; ++i)
#pragma unroll
            for (int j = 0; j < 4; ++j) acc[i][j] = 0.f;
        for (int kc = 0; kc < ED / KC; ++kc) {
            __syncthreads();
#pragma unroll
            for (int p = 0; p < 4; ++p) {
                int f = p * 256 + tid;
                int k = f >> 4;
                int g = f & 15;
                float4 v;
                v.x = w[(size_t)(c0 + g * 4 + 0) * ED + kc * KC + k];
                v.y = w[(size_t)(c0 + g * 4 + 1) * ED + kc * KC + k];
                v.z = w[(size_t)(c0 + g * 4 + 2) * ED + kc * KC + k];
                v.w = w[(size_t)(c0 + g * 4 + 3) * ED + kc * KC + k];
                *reinterpret_cast<float4*>(&wsh[k][g * 4]) = v;
            }
            __syncthreads();
#pragma unroll 8
            for (int k = 0; k < KC; ++k) {
                float4 zv = *reinterpret_cast<const float4*>(&zs[kc * KC + k][tg * 4]);
                float4 wv = *reinterpret_cast<const float4*>(&wsh[k][cg * 4]);
                float zr[4] = { zv.x, zv.y, zv.z, zv.w };
                float wr[4] = { wv.x, wv.y, wv.z, wv.w };
#pragma unroll
                for (int i = 0; i < 4; ++i)
#pragma unroll
                    for (int j = 0; j < 4; ++j)
                        acc[i][j] = fmaf(zr[i], wr[j], acc[i][j]);
            }
        }
#pragma unroll
        for (int j = 0; j < 4; ++j) {
            int c = c0 + cg * 4 + j;
            float wn = wnorm[c];
#pragma unroll
            for (int i = 0; i < 4; ++i) {
                float s = fmaf(-2.f, acc[i][j], wn);
                if (s < best[i]) { best[i] = s; bidx[i] = c; }
            }
        }
    }
#pragma unroll
    for (int m = 1; m < 16; m <<= 1) {
#pragma unroll
        for (int i = 0; i < 4; ++i) {
            float ov = __shfl_xor(best[i], m, 64);
            int   oi = __shfl_xor(bidx[i], m, 64);
            if (ov < best[i] || (ov == best[i] && oi < bidx[i])) {
                best[i] = ov; bidx[i] = oi;
            }
        }
    }
    if (cg == 0) {
#pragma unroll
        for (int i = 0; i < 4; ++i) {
            int t = row0 + tg * 4 + i;
            idx_out[t] = bidx[i];
            atomicAdd(&counts[bidx[i]], 1);
        }
    }
}

__global__ __launch_bounds__(256) void vq_gather0(const float* __restrict__ w,
                                                  const int* __restrict__ idx,
                                                  float* __restrict__ out) {
    int tid = threadIdx.x;
    int t   = blockIdx.x * 4 + (tid >> 6);
    int c4  = tid & 63;
    int id  = idx[t];
    float4 v = reinterpret_cast<const float4*>(w + (size_t)id * ED)[c4];
    reinterpret_cast<float4*>(out + (size_t)t * ED)[c4] = v;
}
// ============================================================================

extern "C" void kernel_launch(void* const* d_in, const int* in_sizes, int n_in,
                              void* d_out, int out_size, void* d_ws, size_t ws_size,
                              hipStream_t stream) {
    const float* z = (const float*)d_in[0];
    const float* w = (const float*)d_in[1];
    float* out = (float*)d_out;
    char* ws = (char*)d_ws;

    float*          wnorm  = (float*)ws;
    int*            counts = (int*)(ws + 4096);
    unsigned*       wmaxsq = (unsigned*)(ws + 8192);
    unsigned short* wb     = (unsigned short*)(ws + 8448);
    unsigned*       cnt    = (unsigned*)(ws + 532736);
    unsigned*       cand   = (unsigned*)(ws + 1057024);
    const size_t need = 1057024 + (size_t)NT * SLOTS * 4;

    if (ws_size >= need) {
        hipMemsetAsync(wmaxsq, 0, 4, stream);
        vq_prep<<<4, 256, 0, stream>>>(w, wnorm, counts, wb, wmaxsq);
        vq_score9<<<NT / 128, 256, 0, stream>>>(z, wb, wnorm, wmaxsq, cnt, cand);
        vq_refine<<<NT / 4, 256, 0, stream>>>(z, w, wnorm, cnt, cand, counts, out);
        vq_pplx<<<1, 1024, 0, stream>>>(counts, out);
    } else {
        int* idxw = (int*)(ws + 8192);
        vq_prep0<<<(NE + 255) / 256, 256, 0, stream>>>(w, wnorm, counts);
        vq_argmin0<<<NT / TM, 256, 0, stream>>>(z, w, wnorm, idxw, counts);
        vq_gather0<<<NT / 4, 256, 0, stream>>>(w, idxw, out);
        vq_pplx<<<1, 1024, 0, stream>>>(counts, out);
    }
}

// Round 17
// 259.818 us; speedup vs baseline: 1.3710x; 1.0020x over previous
//
#include <hip/hip_runtime.h>
#include <math.h>

#define NE   1024
#define ED   256
#define NT   131072
#define SLOTS 32

#define THR_REL 0.016f
#define THR_ABS 0.02f

typedef __attribute__((ext_vector_type(8))) short short8;
typedef __attribute__((ext_vector_type(4))) float f32x4;

__device__ inline unsigned short f2bf(float f) {
    unsigned u = __float_as_uint(f);
    unsigned r = (u + 0x7FFFu + ((u >> 16) & 1u)) >> 16;   // RNE
    return (unsigned short)r;
}

__device__ inline void gl_lds16(const void* g, void* l) {
    __builtin_amdgcn_global_load_lds(
        (const __attribute__((address_space(1))) unsigned int*)g,
        (__attribute__((address_space(3))) unsigned int*)l, 16, 0, 0);
}

// packed candidate: (q(s~) << 16) | code ; q monotone in s~ so u32-min is
// lexicographic (s~, code)-min. q = floor((s + 1024) * 16), clamped.
__device__ inline unsigned pack_cand(float s, int code) {
    float qf = (s + 1024.f) * 16.f;
    int q = (int)qf;
    q = q < 0 ? 0 : (q > 65535 ? 65535 : q);
    return ((unsigned)q << 16) | (unsigned)code;
}

// ---------------------------------------------------------------------------
// ws layout:
//   0        wnorm  f32[1024]
//   4096     counts int[1024]
//   8192     wmaxsq f32[1]             (zero-init by hipMemsetAsync; atomicMax)
//   8448     wb     bf16[1024*256]    (512 KB) — rows prescaled by -2 (exact)
//   532736   cnt    u32[131072]       (512 KB) — low 8: count, high 24: qcut
//   1057024  cand   u32[131072*32]    (16 MB)   need = 17834240
// ---------------------------------------------------------------------------

__global__ __launch_bounds__(256) void vq_prep(const float* __restrict__ w,
                                               float* __restrict__ wnorm,
                                               int* __restrict__ counts,
                                               unsigned short* __restrict__ wb,
                                               unsigned* __restrict__ wmaxsq) {
    int c = blockIdx.x * 256 + threadIdx.x;
    if (c < NE) {
        const float4* row = reinterpret_cast<const float4*>(w + (size_t)c * ED);
        ushort4* wbr = reinterpret_cast<ushort4*>(wb + (size_t)c * ED);
        float s = 0.f;
#pragma unroll 8
        for (int i = 0; i < ED / 4; ++i) {
            float4 v = row[i];
            s += v.x * v.x + v.y * v.y + v.z * v.z + v.w * v.w;
            ushort4 o;   // prescale by -2 (exact power-of-2 scaling, RNE commutes)
            o.x = f2bf(-2.f * v.x); o.y = f2bf(-2.f * v.y);
            o.z = f2bf(-2.f * v.z); o.w = f2bf(-2.f * v.w);
            wbr[i] = o;
        }
        wnorm[c] = s;
        counts[c] = 0;
        // positive-float bits are monotone as unsigned -> atomicMax works
        atomicMax(wmaxsq, __float_as_uint(s));
    }
}

// W-stationary score kernel: counted-vmcnt 2-deep double buffer, single
// 64-MFMA cluster per stage (8 indep chains) in s_setprio, ONE epilogue per
// 64 codes. wb prescaled by -2, acc initialized from wnorm -> acc IS the
// score. cnt packs {count, qcut} so refine needs NO wave reduction.
__global__ __launch_bounds__(256) void vq_score9(const float* __restrict__ z,
                                                 const unsigned short* __restrict__ wb,
                                                 const float* __restrict__ wnorm,
                                                 const unsigned* __restrict__ wmaxsq,
                                                 unsigned* __restrict__ cnt,
                                                 unsigned* __restrict__ cand) {
    __shared__ __align__(16) unsigned short wlds[2][16384]; // 2 x 32 KB
    __shared__ float wn_lds[NE];                            // 4 KB

    const int tid  = threadIdx.x;
    const int lane = tid & 63;
    const int wv_  = tid >> 6;          // 0..3
    const int l15  = lane & 15;
    const int l4   = lane >> 4;
    const int row0 = blockIdx.x * 128 + wv_ * 32;

    // ---- prologue: issue stage 0 -> buf0 and stage 1 -> buf1 FIRST ----
#pragma unroll
    for (int p = 0; p < 8; ++p) {
        int s  = wv_ * 8 + p;
        int nj = s >> 3, kg = s & 7;
        gl_lds16(wb + (size_t)(nj * 16 + l15) * ED + kg * 32 + l4 * 8,
                 &wlds[0][s * 512]);
    }
#pragma unroll
    for (int p = 0; p < 8; ++p) {
        int s  = wv_ * 8 + p;
        int nj = s >> 3, kg = s & 7;
        gl_lds16(wb + (size_t)(64 + nj * 16 + l15) * ED + kg * 32 + l4 * 8,
                 &wlds[1][s * 512]);
    }

    // wnorm -> LDS (256 threads x float4)
    reinterpret_cast<float4*>(wn_lds)[tid] = reinterpret_cast<const float4*>(wnorm)[tid];

    // ---- Z fragments: B-operand layout (col=token=l15, k=kg*32+l4*8+i) ----
    short8 a[2][8];
    float thrR[2], mn[2];
    int cnt_reg[2];
    {
        float wmax = sqrtf(__uint_as_float(wmaxsq[0]));
#pragma unroll
        for (int mi = 0; mi < 2; ++mi) {
            const float* zr = z + (size_t)(row0 + mi * 16 + l15) * ED;
            float s = 0.f;
#pragma unroll
            for (int kg = 0; kg < 8; ++kg) {
                int k0 = kg * 32 + l4 * 8;
                float4 p = *reinterpret_cast<const float4*>(zr + k0);
                float4 q = *reinterpret_cast<const float4*>(zr + k0 + 4);
                s += p.x * p.x + p.y * p.y + p.z * p.z + p.w * p.w
                   + q.x * q.x + q.y * q.y + q.z * q.z + q.w * q.w;
                short8 t;
                t[0] = (short)f2bf(p.x); t[1] = (short)f2bf(p.y);
                t[2] = (short)f2bf(p.z); t[3] = (short)f2bf(p.w);
                t[4] = (short)f2bf(q.x); t[5] = (short)f2bf(q.y);
                t[6] = (short)f2bf(q.z); t[7] = (short)f2bf(q.w);
                a[mi][kg] = t;
            }
            s += __shfl_xor(s, 16, 64);
            s += __shfl_xor(s, 32, 64);
            thrR[mi] = THR_REL * sqrtf(s) * wmax + THR_ABS;
            mn[mi] = 3.4e38f;
            cnt_reg[mi] = 0;
        }
    }

    asm volatile("s_waitcnt vmcnt(0) lgkmcnt(0)" ::: "memory");
    __builtin_amdgcn_s_barrier();

    for (int st = 0; st < 16; ++st) {
        const int b  = st & 1;
        const int c0 = st * 64;

        // stage(st) proven complete while stage(st+2)'s 8 loads stay in flight
        if (st < 15) {
            asm volatile("s_waitcnt vmcnt(8)" ::: "memory");
        } else {
            asm volatile("s_waitcnt vmcnt(0)" ::: "memory");
        }
        __builtin_amdgcn_s_barrier();

        // ---- acc init from wnorm (4 tiles x 2 mi; codes on rows) ----
        f32x4 acc0A, acc0B, acc1A, acc1B, acc2A, acc2B, acc3A, acc3B;
        {
            float4 w0 = *reinterpret_cast<const float4*>(&wn_lds[c0 + 0 * 16 + l4 * 4]);
            float4 w1 = *reinterpret_cast<const float4*>(&wn_lds[c0 + 1 * 16 + l4 * 4]);
            float4 w2 = *reinterpret_cast<const float4*>(&wn_lds[c0 + 2 * 16 + l4 * 4]);
            float4 w3 = *reinterpret_cast<const float4*>(&wn_lds[c0 + 3 * 16 + l4 * 4]);
            acc0A = {w0.x, w0.y, w0.z, w0.w}; acc0B = acc0A;
            acc1A = {w1.x, w1.y, w1.z, w1.w}; acc1B = acc1A;
            acc2A = {w2.x, w2.y, w2.z, w2.w}; acc2B = acc2A;
            acc3A = {w3.x, w3.y, w3.z, w3.w}; acc3B = acc3A;
        }

        // ---- single 64-MFMA cluster, 8 independent chains ----
        __builtin_amdgcn_s_setprio(1);
#pragma unroll
        for (int kg = 0; kg < 8; ++kg) {
            short8 wf0 = *reinterpret_cast<const short8*>(
                &wlds[b][((0 * 8 + kg) * 512) + lane * 8]);
            acc0A = __builtin_amdgcn_mfma_f32_16x16x32_bf16(wf0, a[0][kg], acc0A, 0, 0, 0);
            acc0B = __builtin_amdgcn_mfma_f32_16x16x32_bf16(wf0, a[1][kg], acc0B, 0, 0, 0);
            short8 wf1 = *reinterpret_cast<const short8*>(
                &wlds[b][((1 * 8 + kg) * 512) + lane * 8]);
            acc1A = __builtin_amdgcn_mfma_f32_16x16x32_bf16(wf1, a[0][kg], acc1A, 0, 0, 0);
            acc1B = __builtin_amdgcn_mfma_f32_16x16x32_bf16(wf1, a[1][kg], acc1B, 0, 0, 0);
            short8 wf2 = *reinterpret_cast<const short8*>(
                &wlds[b][((2 * 8 + kg) * 512) + lane * 8]);
            acc2A = __builtin_amdgcn_mfma_f32_16x16x32_bf16(wf2, a[0][kg], acc2A, 0, 0, 0);
            acc2B = __builtin_amdgcn_mfma_f32_16x16x32_bf16(wf2, a[1][kg], acc2B, 0, 0, 0);
            short8 wf3 = *reinterpret_cast<const short8*>(
                &wlds[b][((3 * 8 + kg) * 512) + lane * 8]);
            acc3A = __builtin_amdgcn_mfma_f32_16x16x32_bf16(wf3, a[0][kg], acc3A, 0, 0, 0);
            acc3B = __builtin_amdgcn_mfma_f32_16x16x32_bf16(wf3, a[1][kg], acc3B, 0, 0, 0);
        }
        __builtin_amdgcn_s_setprio(0);

        // ---- ONE epilogue over all 64 codes ----
        float tmin[2];
        {
            f32x4 m0 = acc0A, m1 = acc1A;
#pragma unroll
            for (int r = 0; r < 4; ++r) {
                m0[r] = fminf(m0[r], acc2A[r]);
                m1[r] = fminf(m1[r], acc3A[r]);
            }
            float v = fminf(fminf(m0[0], m0[1]), fminf(m0[2], m0[3]));
            v = fminf(v, fminf(fminf(m1[0], m1[1]), fminf(m1[2], m1[3])));
            tmin[0] = v;
            f32x4 n0 = acc0B, n1 = acc1B;
#pragma unroll
            for (int r = 0; r < 4; ++r) {
                n0[r] = fminf(n0[r], acc2B[r]);
                n1[r] = fminf(n1[r], acc3B[r]);
            }
            float u = fminf(fminf(n0[0], n0[1]), fminf(n0[2], n0[3]));
            u = fminf(u, fminf(fminf(n1[0], n1[1]), fminf(n1[2], n1[3])));
            tmin[1] = u;
        }
#pragma unroll
        for (int mi = 0; mi < 2; ++mi) {
            float v = tmin[mi];
            v = fminf(v, __shfl_xor(v, 16, 64));
            v = fminf(v, __shfl_xor(v, 32, 64));
            mn[mi] = fminf(mn[mi], v);
        }

        // keep masks: bit t*4+r (t = tile 0..3)
        unsigned km[2] = {0u, 0u};
#pragma unroll
        for (int r = 0; r < 4; ++r) {
            if (acc0A[r] <= mn[0] + thrR[0]) km[0] |= 1u << (0 + r);
            if (acc1A[r] <= mn[0] + thrR[0]) km[0] |= 1u << (4 + r);
            if (acc2A[r] <= mn[0] + thrR[0]) km[0] |= 1u << (8 + r);
            if (acc3A[r] <= mn[0] + thrR[0]) km[0] |= 1u << (12 + r);
            if (acc0B[r] <= mn[1] + thrR[1]) km[1] |= 1u << (0 + r);
            if (acc1B[r] <= mn[1] + thrR[1]) km[1] |= 1u << (4 + r);
            if (acc2B[r] <= mn[1] + thrR[1]) km[1] |= 1u << (8 + r);
            if (acc3B[r] <= mn[1] + thrR[1]) km[1] |= 1u << (12 + r);
        }

        if (__any((km[0] | km[1]) != 0u)) {
#pragma unroll
            for (int mi = 0; mi < 2; ++mi) {
                int kc = __popc(km[mi]);
                int b2 = __shfl_xor(kc, 16, 64);   // l4 ^ 1
                int c2 = __shfl_xor(kc, 32, 64);   // l4 ^ 2
                int d2 = __shfl_xor(b2, 32, 64);   // l4 ^ 3
                int tot = kc + b2 + c2 + d2;
                if (tot > 0) {
                    int pfx = (l4 == 1) ? b2
                            : (l4 == 2) ? (c2 + d2)
                            : (l4 == 3) ? (b2 + c2 + d2) : 0;
                    int tok = row0 + mi * 16 + l15;
                    int o = 0;
                    const f32x4* accs[4] = {
                        mi == 0 ? &acc0A : &acc0B,
                        mi == 0 ? &acc1A : &acc1B,
                        mi == 0 ? &acc2A : &acc2B,
                        mi == 0 ? &acc3A : &acc3B };
#pragma unroll
                    for (int t = 0; t < 4; ++t)
#pragma unroll
                        for (int r = 0; r < 4; ++r)
                            if (km[mi] & (1u << (t * 4 + r))) {
                                int pos = cnt_reg[mi] + pfx + o;
                                if (pos < SLOTS)
                                    cand[(size_t)tok * SLOTS + pos] =
                                        pack_cand((*accs[t])[r],
                                                  c0 + t * 16 + l4 * 4 + r);
                                ++o;
                            }
                    cnt_reg[mi] += tot;
                }
            }
        }

        // release buf[b], then issue stage(st+2) into it (stays in flight
        // across the next loop-top vmcnt(8), covered by compute(st+1)).
        asm volatile("s_waitcnt lgkmcnt(0)" ::: "memory");
        __builtin_amdgcn_s_barrier();
        if (st + 2 < 16) {
            const int cN = (st + 2) * 64;
#pragma unroll
            for (int p = 0; p < 8; ++p) {
                int s  = wv_ * 8 + p;
                int nj = s >> 3, kg = s & 7;
                gl_lds16(wb + (size_t)(cN + nj * 16 + l15) * ED + kg * 32 + l4 * 8,
                         &wlds[b][s * 512]);
            }
        }
    }

    // final per-token {count, qcut} (4 l4-lanes agree; l4==0 writes).
    // qcut = q(mn + thr) + 2: every candidate with exact-score <= true min
    // has q <= qcut (same +-1-quantum slack as the old margin criterion).
    if (l4 == 0) {
#pragma unroll
        for (int mi = 0; mi < 2; ++mi) {
            unsigned n = (unsigned)cnt_reg[mi];
            if (n > 255u) n = 255u;
            float qc = (mn[mi] + thrR[mi] + 1024.f) * 16.f;
            int qi = (int)qc;
            qi = qi < 0 ? 0 : qi;
            unsigned qcut = (unsigned)qi + 2u;
            cnt[row0 + mi * 16 + l15] = n | (qcut << 8);
        }
    }
}

// Exact fp32 refine: per-lane keep test against the precomputed qcut — NO
// wave reduction. cnt and cand loads issued in parallel. Sole survivor ==
// exact argmin -> direct gather (no z read).
__global__ __launch_bounds__(256) void vq_refine(const float* __restrict__ z,
                                                 const float* __restrict__ w,
                                                 const float* __restrict__ wnorm,
                                                 const unsigned* __restrict__ cnt,
                                                 const unsigned* __restrict__ cand,
                                                 int* __restrict__ counts,
                                                 float* __restrict__ out) {
    const int lane = threadIdx.x & 63;
    const int t = blockIdx.x * 4 + (threadIdx.x >> 6);

    // both loads independent -> issue in parallel
    const unsigned tpack = cnt[t];
    const unsigned pk = (lane < SLOTS) ? cand[(size_t)t * SLOTS + lane]
                                       : 0xFFFFFFFFu;
    const unsigned n    = tpack & 0xFFu;
    const unsigned qcut = tpack >> 8;

    int bj = NE;
    bool need_exact = true;
    unsigned long long mask = 0ull;

    if (n >= 1u && n <= (unsigned)SLOTS) {
        bool keep = (lane < (int)n) && ((pk >> 16) <= qcut);
        mask = __ballot(keep);
        if (__popcll(mask) == 1) {
            int c = __ffsll(mask) - 1;
            bj = (int)(__shfl(pk, c, 64) & 0xFFFFu);
            need_exact = false;          // sole survivor == exact argmin
        }
    }

    if (need_exact) {
        float4 zv = reinterpret_cast<const float4*>(z + (size_t)t * ED)[lane];
        float bs = 3.4e38f;
        bj = NE;
        if (n >= 1u && n <= (unsigned)SLOTS) {
            unsigned long long m2 = mask;
            while (m2) {
                int c = __ffsll(m2) - 1;
                m2 &= m2 - 1;
                int j = (int)(__shfl(pk, c, 64) & 0xFFFFu);
                float4 wv = reinterpret_cast<const float4*>(w + (size_t)j * ED)[lane];
                float d = fmaf(zv.x, wv.x, fmaf(zv.y, wv.y, fmaf(zv.z, wv.z, zv.w * wv.w)));
#pragma unroll
                for (int m = 1; m < 64; m <<= 1) d += __shfl_xor(d, m, 64);
                float s = fmaf(-2.f, d, wnorm[j]);
                if (s < bs || (s == bs && j < bj)) { bs = s; bj = j; }
            }
        } else {
            for (int j = 0; j < NE; ++j) {
                float4 wv = reinterpret_cast<const float4*>(w + (size_t)j * ED)[lane];
                float d = fmaf(zv.x, wv.x, fmaf(zv.y, wv.y, fmaf(zv.z, wv.z, zv.w * wv.w)));
#pragma unroll
                for (int m = 1; m < 64; m <<= 1) d += __shfl_xor(d, m, 64);
                float s = fmaf(-2.f, d, wnorm[j]);
                if (s < bs || (s == bs && j < bj)) { bs = s; bj = j; }
            }
        }
    }

    float4 bw = reinterpret_cast<const float4*>(w + (size_t)bj * ED)[lane];
    reinterpret_cast<float4*>(out + (size_t)t * ED)[lane] = bw;
    if (lane == 0) atomicAdd(&counts[bj], 1);
}

__global__ __launch_bounds__(1024) void vq_pplx(const int* __restrict__ counts,
                                                float* __restrict__ out) {
    __shared__ float red[16];
    int tid = threadIdx.x;
    float e = (float)counts[tid] * (1.0f / (float)NT);
    float t = -e * logf(e + 1e-10f);
#pragma unroll
    for (int m = 32; m >= 1; m >>= 1) t += __shfl_down(t, m, 64);
    if ((tid & 63) == 0) red[tid >> 6] = t;
    __syncthreads();
    if (tid < 16) {
        float s = red[tid];
#pragma unroll
        for (int m = 8; m >= 1; m >>= 1) s += __shfl_down(s, m, 16);
        if (tid == 0) out[(size_t)NT * ED] = expf(s);
    }
}

// ======================= fallback (round-1, fp32 VALU) =======================
#define TM 64
#define TN 64
#define KC 64

__global__ __launch_bounds__(256) void vq_prep0(const float* __restrict__ w,
                                                float* __restrict__ wnorm,
                                                int* __restrict__ counts) {
    int c = blockIdx.x * blockDim.x + threadIdx.x;
    if (c < NE) {
        const float4* row = reinterpret_cast<const float4*>(w + (size_t)c * ED);
        float s = 0.f;
#pragma unroll 8
        for (int i = 0; i < ED / 4; ++i) {
            float4 v = row[i];
            s += v.x * v.x + v.y * v.y + v.z * v.z + v.w * v.w;
        }
        wnorm[c] = s;
        counts[c] = 0;
    }
}

__global__ __launch_bounds__(256) void vq_argmin0(const float* __restrict__ z,
                                                  const float* __restrict__ w,
                                                  const float* __restrict__ wnorm,
                                                  int* __restrict__ idx_out,
                                                  int* __restrict__ counts) {
    __shared__ float zs[ED][TM];
    __shared__ float wsh[KC][TN];
    const int tid  = threadIdx.x;
    const int row0 = blockIdx.x * TM;
    const int cg   = tid & 15;
    const int tg   = tid >> 4;
#pragma unroll
    for (int p = 0; p < 16; ++p) {
        int f = p * 256 + tid;
        int k = f >> 4;
        int g = f & 15;
        float4 v;
        v.x = z[(size_t)(row0 + g * 4 + 0) * ED + k];
        v.y = z[(size_t)(row0 + g * 4 + 1) * ED + k];
        v.z = z[(size_t)(row0 + g * 4 + 2) * ED + k];
        v.w = z[(size_t)(row0 + g * 4 + 3) * ED + k];
        *reinterpret_cast<float4*>(&zs[k][g * 4]) = v;
    }
    float best[4];
    int   bidx[4];
#pragma unroll
    for (int i = 0; i < 4; ++i) { best[i] = 3.4e38f; bidx[i] = 0; }
    for (int ct = 0; ct < NE / TN; ++ct) {
        const int c0 = ct * TN;
        float acc[4][4];
#pragma unroll
        for (int i = 0; i < 4; ++i)
#pragma unroll
            for (int j = 0; j < 4; ++j) acc[i][j] = 0.f;
        for (int kc = 0; kc < ED / KC; ++kc) {
            __syncthreads();
#pragma unroll
            for (int p = 0; p < 4; ++p) {
                int f = p * 256 + tid;
                int k = f >> 4;
                int g = f & 15;
                float4 v;
                v.x = w[(size_t)(c0 + g * 4 + 0) * ED + kc * KC + k];
                v.y = w[(size_t)(c0 + g * 4 + 1) * ED + kc * KC + k];
                v.z = w[(size_t)(c0 + g * 4 + 2) * ED + kc * KC + k];
                v.w = w[(size_t)(c0 + g * 4 + 3) * ED + kc * KC + k];
                *reinterpret_cast<float4*>(&wsh[k][g * 4]) = v;
            }
            __syncthreads();
#pragma unroll 8
            for (int k = 0; k < KC; ++k) {
                float4 zv = *reinterpret_cast<const float4*>(&zs[kc * KC + k][tg * 4]);
                float4 wv = *reinterpret_cast<const float4*>(&wsh[k][cg * 4]);
                float zr[4] = { zv.x, zv.y, zv.z, zv.w };
                float wr[4] = { wv.x, wv.y, wv.z, wv.w };
#pragma unroll
                for (int i = 0; i < 4; ++i)
#pragma unroll
                    for (int j = 0; j < 4; ++j)
                        acc[i][j] = fmaf(zr[i], wr[j], acc[i][j]);
            }
        }
#pragma unroll
        for (int j = 0; j < 4; ++j) {
            int c = c0 + cg * 4 + j;
            float wn = wnorm[c];
#pragma unroll
            for (int i = 0; i < 4; ++i) {
                float s = fmaf(-2.f, acc[i][j], wn);
                if (s < best[i]) { best[i] = s; bidx[i] = c; }
            }
        }
    }
#pragma unroll
    for (int m = 1; m < 16; m <<= 1) {
#pragma unroll
        for (int i = 0; i < 4; ++i) {
            float ov = __shfl_xor(best[i], m, 64);
            int   oi = __shfl_xor(bidx[i], m, 64);
            if (ov < best[i] || (ov == best[i] && oi < bidx[i])) {
                best[i] = ov; bidx[i] = oi;
            }
        }
    }
    if (cg == 0) {
#pragma unroll
        for (int i = 0; i < 4; ++i) {
            int t = row0 + tg * 4 + i;
            idx_out[t] = bidx[i];
            atomicAdd(&counts[bidx[i]], 1);
        }
    }
}

__global__ __launch_bounds__(256) void vq_gather0(const float* __restrict__ w,
                                                  const int* __restrict__ idx,
                                                  float* __restrict__ out) {
    int tid = threadIdx.x;
    int t   = blockIdx.x * 4 + (tid >> 6);
    int c4  = tid & 63;
    int id  = idx[t];
    float4 v = reinterpret_cast<const float4*>(w + (size_t)id * ED)[c4];
    reinterpret_cast<float4*>(out + (size_t)t * ED)[c4] = v;
}
// ============================================================================

extern "C" void kernel_launch(void* const* d_in, const int* in_sizes, int n_in,
                              void* d_out, int out_size, void* d_ws, size_t ws_size,
                              hipStream_t stream) {
    const float* z = (const float*)d_in[0];
    const float* w = (const float*)d_in[1];
    float* out = (float*)d_out;
    char* ws = (char*)d_ws;

    float*          wnorm  = (float*)ws;
    int*            counts = (int*)(ws + 4096);
    unsigned*       wmaxsq = (unsigned*)(ws + 8192);
    unsigned short* wb     = (unsigned short*)(ws + 8448);
    unsigned*       cnt    = (unsigned*)(ws + 532736);
    unsigned*       cand   = (unsigned*)(ws + 1057024);
    const size_t need = 1057024 + (size_t)NT * SLOTS * 4;

    if (ws_size >= need) {
        hipMemsetAsync(wmaxsq, 0, 4, stream);
        vq_prep<<<4, 256, 0, stream>>>(w, wnorm, counts, wb, wmaxsq);
        vq_score9<<<NT / 128, 256, 0, stream>>>(z, wb, wnorm, wmaxsq, cnt, cand);
        vq_refine<<<NT / 4, 256, 0, stream>>>(z, w, wnorm, cnt, cand, counts, out);
        vq_pplx<<<1, 1024, 0, stream>>>(counts, out);
    } else {
        int* idxw = (int*)(ws + 8192);
        vq_prep0<<<(NE + 255) / 256, 256, 0, stream>>>(w, wnorm, counts);
        vq_argmin0<<<NT / TM, 256, 0, stream>>>(z, w, wnorm, idxw, counts);
        vq_gather0<<<NT / 4, 256, 0, stream>>>(w, idxw, out);
        vq_pplx<<<1, 1024, 0, stream>>>(counts, out);
    }
}